// Round 4
// baseline (426.164 us; speedup 1.0000x reference)
//
#include <hip/hip_runtime.h>
#include <stdint.h>

// LocalAttention: y = LN(x + proj(attn(qkv(x)))). fp32 inputs, fp32 output.
// B=4 L=4096 D=1024 H=16 W=HD=64 -> M=16384 rows.
//
// R11: register-feasible occupancy fix. R10's (512,4) bound demanded <=128
// regs/wave while the 256-tile path needs 128 acc AGPRs alone -> forced
// spill -> suspected harness failure. Per-wave output must be 64x64
// (64 acc regs) for >2 waves/SIMD. So: 4-wave 128x128 tile (R7-proven
// fragment layout, 88 VGPR + 64 AGPR = 152 regs -> 3 waves/SIMD), BK=32
// double-buffer = 32 KiB LDS -> 3 blocks/CU resident; R9-proven 2-barrier
// K-loop with counted vmcnt(4) one-tile-ahead global_load_lds prefetch;
// XOR-4 LDS swizzle (0 conflicts measured); XCD-bijective block swizzle.
// Attn: 4 windows per block sequentially (grid 1024), barrier pair per
// window (Vt staged->PV ; PV done->next overwrite). P is per-wave-private.

typedef __attribute__((ext_vector_type(8))) short short8;
typedef __attribute__((ext_vector_type(4))) float float4v;
typedef unsigned short us;

#define GAS const __attribute__((address_space(1))) void
#define LAS __attribute__((address_space(3))) void

__device__ __forceinline__ float bf2f(us u) {
  return __uint_as_float(((unsigned int)u) << 16);
}
__device__ __forceinline__ us f2bf(float f) {
  unsigned int u = __float_as_uint(f);
  unsigned int r = u + 0x7FFFu + ((u >> 16) & 1u);
  return (us)(r >> 16);
}
__device__ __forceinline__ int4 stage8(const float* p) {
  float4 a = *(const float4*)p;
  float4 b = *(const float4*)(p + 4);
  int4 r;
  us* u = (us*)&r;
  u[0] = f2bf(a.x); u[1] = f2bf(a.y); u[2] = f2bf(a.z); u[3] = f2bf(a.w);
  u[4] = f2bf(b.x); u[5] = f2bf(b.y); u[6] = f2bf(b.z); u[7] = f2bf(b.w);
  return r;
}
__device__ __forceinline__ int4 stage8(const us* p) { return *(const int4*)p; }
__device__ __forceinline__ void stc(us* p, float v) { *p = f2bf(v); }
__device__ __forceinline__ void stc(float* p, float v) { *p = v; }

// ---------------------------------------------------------------------------
// fp32 -> bf16 precast, 8 elems/thread
// ---------------------------------------------------------------------------
__global__ __launch_bounds__(256) void cast_bf16(const float* __restrict__ src,
                                                 us* __restrict__ dst, int n8) {
  const int i = blockIdx.x * 256 + threadIdx.x;
  if (i < n8) *(int4*)(dst + (size_t)i * 8) = stage8(src + (size_t)i * 8);
}

// ---------------------------------------------------------------------------
// 128x128 GEMM, BK=32, 4 waves (2x2, per-wave 64x64 = 64 acc regs).
// C = A @ Bt^T + bias (+resid). LDS: 2-deep double buffer, 32 KiB total
// -> 3 blocks/CU (reg-capped; LDS would allow 5). K-loop per tile t:
//   B0 barrier -> all waves finished reading tile t-1 (its buffer free)
//   STAGE(t+1) -> 4 global_load_lds into buf[cur^1]
//   vmcnt(4)   -> tile t's 4 loads landed; t+1's stay in flight
//   B1 barrier -> tile t visible to all waves
//   compute    -> 8 ds_read_b128 + 16 MFMA, no barriers
// Swizzle: logical 16B-group g of row r stored at phys group g^(r&3);
// staging pre-swizzles the SOURCE col (flat lane-order DMA dest); fragment
// reads apply the same XOR. XCD swizzle: (id&7)*(NWG/8)+(id>>3), NWG%8==0.
// HM: head-major C store [mat][b*16+h][tok][d] for the QKV gemm.
// ---------------------------------------------------------------------------
template <int N, int K, int EPI, int HM, typename CT>
__global__ __launch_bounds__(256) void gemm128(
    const us* __restrict__ A, const us* __restrict__ Bt,
    const float* __restrict__ bias, const float* __restrict__ resid,
    CT* __restrict__ C) {
  constexpr int NBX = N / 128;
  constexpr int NBY = 128;  // 16384/128
  constexpr int NWG = NBX * NBY;
  __shared__ __align__(16) us As[2][128 * 32];
  __shared__ __align__(16) us Bs[2][128 * 32];
  const int tid = threadIdx.x;
  const int lane = tid & 63;
  const int wave = tid >> 6;
  const int wm = wave >> 1, wn = wave & 1;
  const int lr = lane & 15, lq = lane >> 4;

  int id = blockIdx.y * NBX + blockIdx.x;
  id = (id & 7) * (NWG / 8) + (id >> 3);  // XCD-contiguous tile ranges
  const int m0 = (id / NBX) * 128;
  const int n0 = (id % NBX) * 128;

  const int srow = tid >> 2;                        // 0..63 (row within pass)
  const int scol = (((tid & 3) ^ (srow & 3)) * 8);  // XOR-swizzled src col

  constexpr int NT = K / 32;

  float4v acc[4][4];
#pragma unroll
  for (int i = 0; i < 4; i++)
#pragma unroll
    for (int j = 0; j < 4; j++) acc[i][j] = (float4v)0.0f;

#define STG128(buf, t)                                                         \
  do {                                                                         \
    const size_t kof = (size_t)(t) * 32;                                       \
    _Pragma("unroll") for (int p = 0; p < 2; p++) {                            \
      const us* ga = A + (size_t)(m0 + p * 64 + srow) * K + kof + scol;        \
      __builtin_amdgcn_global_load_lds((GAS*)ga,                               \
          (LAS*)&As[buf][(p * 256 + tid) * 8], 16, 0, 0);                      \
    }                                                                          \
    _Pragma("unroll") for (int p = 0; p < 2; p++) {                            \
      const us* gb = Bt + (size_t)(n0 + p * 64 + srow) * K + kof + scol;       \
      __builtin_amdgcn_global_load_lds((GAS*)gb,                               \
          (LAS*)&Bs[buf][(p * 256 + tid) * 8], 16, 0, 0);                      \
    }                                                                          \
  } while (0)

  STG128(0, 0);  // prologue: tile 0 in flight

  for (int t = 0; t < NT; t++) {
    const int cur = t & 1;
    __builtin_amdgcn_s_barrier();  // B0: tile t-1 reads complete everywhere
    if (t + 1 < NT) {
      STG128(cur ^ 1, t + 1);      // overwrite t-1's buffer (safe after B0)
      asm volatile("s_waitcnt vmcnt(4)" ::: "memory");  // tile t landed
    } else {
      asm volatile("s_waitcnt vmcnt(0)" ::: "memory");  // drain last tile
    }
    __builtin_amdgcn_s_barrier();  // B1: tile t visible to all waves

    const us* Ab = As[cur];
    const us* Bb = Bs[cur];
    short8 af[4], bf8[4];
#pragma unroll
    for (int mt = 0; mt < 4; mt++)
      af[mt] = *(const short8*)&Ab[(wm * 64 + mt * 16 + lr) * 32 +
                                   ((lq ^ (lr & 3)) * 8)];
#pragma unroll
    for (int nt = 0; nt < 4; nt++)
      bf8[nt] = *(const short8*)&Bb[(wn * 64 + nt * 16 + lr) * 32 +
                                    ((lq ^ (lr & 3)) * 8)];
    __builtin_amdgcn_s_setprio(1);
#pragma unroll
    for (int mt = 0; mt < 4; mt++)
#pragma unroll
      for (int nt = 0; nt < 4; nt++)
        acc[mt][nt] = __builtin_amdgcn_mfma_f32_16x16x32_bf16(
            af[mt], bf8[nt], acc[mt][nt], 0, 0, 0);
    __builtin_amdgcn_s_setprio(0);
  }
#undef STG128

  float bb[4];
#pragma unroll
  for (int nt = 0; nt < 4; nt++) bb[nt] = bias[n0 + wn * 64 + nt * 16 + lr];
#pragma unroll
  for (int mt = 0; mt < 4; mt++) {
    const int rbase = m0 + wm * 64 + mt * 16 + lq * 4;
#pragma unroll
    for (int nt = 0; nt < 4; nt++) {
      const int col = n0 + wn * 64 + nt * 16 + lr;
#pragma unroll
      for (int r = 0; r < 4; r++) {
        float v = acc[mt][nt][r] + bb[nt];
        const int row = rbase + r;
        size_t idx;
        if (HM) {
          // head-major: [mat][b*16+h][tok][d]
          const int mat = col >> 10, hh = (col >> 6) & 15, d = col & 63;
          idx = (size_t)mat * (16384u * 1024u) +
                (size_t)((row >> 12) * 16 + hh) * (4096u * 64u) +
                (size_t)(row & 4095) * 64 + d;
        } else {
          idx = (size_t)row * N + col;
        }
        if (EPI) v += resid[idx];
        stc(&C[idx], v);
      }
    }
  }
}

// ---------------------------------------------------------------------------
// MFMA windowed attention, head-major input, 4 windows per block.
// One block (4 waves) processes windows g0..g0+3 of the same (b,h)
// sequentially. Per window: stage V^T (cross-wave) -> S=QK^T from global
// (L1-local contiguous 8KB tiles) -> in-register softmax -> P to per-wave
// LDS -> barrier (Vt ready) -> O=PV -> store -> barrier (Vt reads done,
// next window may overwrite). P is per-wave-private (no sync needed).
// ---------------------------------------------------------------------------
__global__ __launch_bounds__(256) void attn_mfma(
    const us* __restrict__ qkv, us* __restrict__ attn) {
  __shared__ __align__(16) us Vt[64 * 64];       // elem(d,j) at d*64+((j>>3)^(d&7))*8+(j&7)
  __shared__ __align__(16) us Pl[4 * 16 * 64];   // per-wave 16x64, same swizzle
  const int g0 = blockIdx.x * 4;
  const int h = (g0 >> 6) & 15;   // constant over the 4 windows (4 | 64)
  const int b = g0 >> 10;
  const int tid = threadIdx.x;
  const int lane = tid & 63;
  const int w = tid >> 6;
  const int lr = lane & 15, lq = lane >> 4;

  const us* Qh = qkv + (size_t)(b * 16 + h) * (4096u * 64u);
  const us* Kh = Qh + (size_t)16384 * 1024;
  const us* Vh = Kh + (size_t)16384 * 1024;

  for (int i = 0; i < 4; i++) {
    const int wi = (g0 + i) & 63;
    const int rowbase = b * 4096 + wi * 64;
    const us* Qb = Qh + (size_t)wi * 4096;
    const us* Kb = Kh + (size_t)wi * 4096;
    const us* Vb = Vh + (size_t)wi * 4096;

    // ---- stage V^T (swizzled): wave w covers d in [16w,16w+16)
    {
      const int r = lane;  // token in window
      const int cs = w * 16;
      const us* vsrc = Vb + (size_t)r * 64 + cs;
      int4 v0 = *(const int4*)vsrc;
      int4 v1 = *(const int4*)(vsrc + 8);
      const us* vv0 = (const us*)&v0;
      const us* vv1 = (const us*)&v1;
#pragma unroll
      for (int k = 0; k < 8; k++) {
        const int d = cs + k;
        Vt[d * 64 + (((r >> 3) ^ (d & 7)) * 8) + (r & 7)] = vv0[k];
      }
#pragma unroll
      for (int k = 0; k < 8; k++) {
        const int d = cs + 8 + k;
        Vt[d * 64 + (((r >> 3) ^ (d & 7)) * 8) + (r & 7)] = vv1[k];
      }
    }

    // ---- S = Q K^T (rows 16w..16w+15), frags from global (L1-local)
    short8 aq[2];
    {
      const us* qrow = Qb + (size_t)(w * 16 + lr) * 64 + lq * 8;
      aq[0] = *(const short8*)qrow;
      aq[1] = *(const short8*)(qrow + 32);
    }
    float4v s[4];
#pragma unroll
    for (int nt = 0; nt < 4; nt++) s[nt] = (float4v)0.0f;
#pragma unroll
    for (int kk8 = 0; kk8 < 2; kk8++) {
#pragma unroll
      for (int nt = 0; nt < 4; nt++) {
        const us* krow = Kb + (size_t)(nt * 16 + lr) * 64 + kk8 * 32 + lq * 8;
        short8 bk = *(const short8*)krow;
        s[nt] = __builtin_amdgcn_mfma_f32_16x16x32_bf16(aq[kk8], bk, s[nt], 0, 0, 0);
      }
    }

    // ---- softmax per row
    float p[4][4];  // [nt][r]
#pragma unroll
    for (int r = 0; r < 4; r++) {
      float mx = -1e30f;
#pragma unroll
      for (int nt = 0; nt < 4; nt++) {
        s[nt][r] *= 0.125f;
        mx = fmaxf(mx, s[nt][r]);
      }
      mx = fmaxf(mx, __shfl_xor(mx, 1));
      mx = fmaxf(mx, __shfl_xor(mx, 2));
      mx = fmaxf(mx, __shfl_xor(mx, 4));
      mx = fmaxf(mx, __shfl_xor(mx, 8));
      float sum = 0.f;
#pragma unroll
      for (int nt = 0; nt < 4; nt++) {
        p[nt][r] = __expf(s[nt][r] - mx);
        sum += p[nt][r];
      }
      sum += __shfl_xor(sum, 1);
      sum += __shfl_xor(sum, 2);
      sum += __shfl_xor(sum, 4);
      sum += __shfl_xor(sum, 8);
      const float inv = 1.0f / sum;
#pragma unroll
      for (int nt = 0; nt < 4; nt++) p[nt][r] *= inv;
    }

    // ---- P -> LDS (per-wave region, swizzled), C-layout source
    us* pw = Pl + w * 1024;
#pragma unroll
    for (int nt = 0; nt < 4; nt++) {
      const int c = nt * 16 + lr;
#pragma unroll
      for (int r = 0; r < 4; r++) {
        const int row = lq * 4 + r;
        pw[row * 64 + (((c >> 3) ^ (row & 7)) * 8) + (c & 7)] = f2bf(p[nt][r]);
      }
    }
    __syncthreads();  // Vt (cross-wave) staged; P (own-wave) ordered by lgkm

    // ---- O = P V  (A-frag from Pl, B-frag from Vt)
    float4v o[4];
#pragma unroll
    for (int nt = 0; nt < 4; nt++) o[nt] = (float4v)0.0f;
#pragma unroll
    for (int kk8 = 0; kk8 < 2; kk8++) {
      short8 pa = *(const short8*)&pw[lr * 64 + (((lq + kk8 * 4) ^ (lr & 7)) * 8)];
#pragma unroll
      for (int nt = 0; nt < 4; nt++) {
        const int d = nt * 16 + lr;
        short8 vb = *(const short8*)&Vt[d * 64 + (((lq + kk8 * 4) ^ (d & 7)) * 8)];
        o[nt] = __builtin_amdgcn_mfma_f32_16x16x32_bf16(pa, vb, o[nt], 0, 0, 0);
      }
    }

    // ---- store O (C-layout): row = 16w+lq*4+r, col d = nt*16+lr
#pragma unroll
    for (int nt = 0; nt < 4; nt++) {
      const int d = nt * 16 + lr;
#pragma unroll
      for (int r = 0; r < 4; r++) {
        const int tok = rowbase + w * 16 + lq * 4 + r;
        attn[(size_t)tok * 1024 + h * 64 + d] = f2bf(o[nt][r]);
      }
    }
    if (i < 3) __syncthreads();  // Vt reads done before next window's writes
  }
}

// ---------------------------------------------------------------------------
// FALLBACK GEMM (R5-proven, VGPR staging + convert, unswizzled)
// ---------------------------------------------------------------------------
template <int N, int K, int EPI, typename AT, typename CT>
__global__ __launch_bounds__(256) void gemm_bt(
    const AT* __restrict__ A, const float* __restrict__ Bt,
    const float* __restrict__ bias, const float* __restrict__ resid,
    CT* __restrict__ C) {
  __shared__ __align__(16) us As[128 * 64];
  __shared__ __align__(16) us Bs[128 * 64];
  const int tid = threadIdx.x;
  const int lane = tid & 63;
  const int wave = tid >> 6;
  const int wm = wave >> 1, wn = wave & 1;
  const int lr = lane & 15, lq = lane >> 4;
  const int m0 = blockIdx.y * 128;
  const int n0 = blockIdx.x * 128;
  const int trow = tid >> 3;
  const int tcol = (tid & 7) * 8;

  float4v acc[4][4];
#pragma unroll
  for (int i = 0; i < 4; i++)
#pragma unroll
    for (int j = 0; j < 4; j++) acc[i][j] = (float4v)0.0f;

  for (int k0 = 0; k0 < K; k0 += 64) {
    int4 av[4], bv[4];
#pragma unroll
    for (int p = 0; p < 4; p++) {
      av[p] = stage8(A + (size_t)(m0 + p * 32 + trow) * K + k0 + tcol);
      bv[p] = stage8(Bt + (size_t)(n0 + p * 32 + trow) * K + k0 + tcol);
    }
#pragma unroll
    for (int p = 0; p < 4; p++) {
      *(int4*)&As[(p * 256 + tid) * 8] = av[p];
      *(int4*)&Bs[(p * 256 + tid) * 8] = bv[p];
    }
    __syncthreads();
#pragma unroll
    for (int kk = 0; kk < 64; kk += 32) {
      short8 af[4], bfv[4];
#pragma unroll
      for (int mt = 0; mt < 4; mt++)
        af[mt] = *(const short8*)&As[(wm * 64 + mt * 16 + lr) * 64 + kk + lq * 8];
#pragma unroll
      for (int nt = 0; nt < 4; nt++)
        bfv[nt] = *(const short8*)&Bs[(wn * 64 + nt * 16 + lr) * 64 + kk + lq * 8];
#pragma unroll
      for (int mt = 0; mt < 4; mt++)
#pragma unroll
        for (int nt = 0; nt < 4; nt++)
          acc[mt][nt] = __builtin_amdgcn_mfma_f32_16x16x32_bf16(
              af[mt], bfv[nt], acc[mt][nt], 0, 0, 0);
    }
    __syncthreads();
  }

  float bb[4];
#pragma unroll
  for (int nt = 0; nt < 4; nt++) bb[nt] = bias[n0 + wn * 64 + nt * 16 + lr];
#pragma unroll
  for (int mt = 0; mt < 4; mt++) {
    const int rbase = m0 + wm * 64 + mt * 16 + lq * 4;
#pragma unroll
    for (int nt = 0; nt < 4; nt++) {
      const int col = n0 + wn * 64 + nt * 16 + lr;
#pragma unroll
      for (int r = 0; r < 4; r++) {
        float v = acc[mt][nt][r] + bb[nt];
        size_t idx = (size_t)(rbase + r) * N + col;
        if (EPI) v += resid[idx];
        stc(&C[idx], v);
      }
    }
  }
}

// ---------------------------------------------------------------------------
// Fallback VALU attention (R5-proven, row-major qkv)
// ---------------------------------------------------------------------------
__global__ __launch_bounds__(256) void attn_win(
    const us* __restrict__ qkv, us* __restrict__ attn) {
  __shared__ float qs[64][65];
  __shared__ float ks[64][65];
  __shared__ float vs[64][65];
  const int wid = blockIdx.x;
  const int wi = wid & 63;
  const int h = (wid >> 6) & 15;
  const int b = wid >> 10;
  const int t = threadIdx.x;
  const int rowbase = b * 4096 + wi * 64;
  {
    const int r = t >> 2;
    const int cs = (t & 3) * 16;
    const us* base = qkv + (size_t)(rowbase + r) * 3072 + h * 64 + cs;
#pragma unroll
    for (int s = 0; s < 3; s++) {
      float* dst = (s == 0) ? &qs[r][cs] : (s == 1) ? &ks[r][cs] : &vs[r][cs];
      const us* src = base + s * 1024;
#pragma unroll
      for (int half = 0; half < 2; half++) {
        int4 dv = *(const int4*)(src + half * 8);
        const us* tp = (const us*)&dv;
#pragma unroll
        for (int i = 0; i < 8; i++) dst[half * 8 + i] = bf2f(tp[i]);
      }
    }
  }
  __syncthreads();
  const int r0 = (t >> 4) * 4;
  const int c0 = (t & 15) * 4;
  float acc[4][4] = {};
#pragma unroll 8
  for (int k = 0; k < 64; k++) {
    float qv[4], kv[4];
#pragma unroll
    for (int i = 0; i < 4; i++) qv[i] = qs[r0 + i][k];
#pragma unroll
    for (int j = 0; j < 4; j++) kv[j] = ks[c0 + j][k];
#pragma unroll
    for (int i = 0; i < 4; i++)
#pragma unroll
      for (int j = 0; j < 4; j++) acc[i][j] += qv[i] * kv[j];
  }
  __syncthreads();
#pragma unroll
  for (int i = 0; i < 4; i++)
#pragma unroll
    for (int j = 0; j < 4; j++) qs[r0 + i][c0 + j] = acc[i][j] * 0.125f;
  __syncthreads();
  {
    const int rr = t >> 2;
    const int cs = (t & 3) * 16;
    float pv[16];
    float m = -1e30f;
#pragma unroll
    for (int i = 0; i < 16; i++) {
      pv[i] = qs[rr][cs + i];
      m = fmaxf(m, pv[i]);
    }
    m = fmaxf(m, __shfl_xor(m, 1));
    m = fmaxf(m, __shfl_xor(m, 2));
    float ssum = 0.f;
#pragma unroll
    for (int i = 0; i < 16; i++) {
      pv[i] = __expf(pv[i] - m);
      ssum += pv[i];
    }
    ssum += __shfl_xor(ssum, 1);
    ssum += __shfl_xor(ssum, 2);
    const float inv = 1.0f / ssum;
#pragma unroll
    for (int i = 0; i < 16; i++) qs[rr][cs + i] = pv[i] * inv;
  }
  __syncthreads();
  float o[4][4] = {};
#pragma unroll 8
  for (int k = 0; k < 64; k++) {
    float pr[4], vv[4];
#pragma unroll
    for (int i = 0; i < 4; i++) pr[i] = qs[r0 + i][k];
#pragma unroll
    for (int j = 0; j < 4; j++) vv[j] = vs[k][c0 + j];
#pragma unroll
    for (int i = 0; i < 4; i++)
#pragma unroll
      for (int j = 0; j < 4; j++) o[i][j] += pr[i] * vv[j];
  }
#pragma unroll
  for (int i = 0; i < 4; i++)
#pragma unroll
    for (int j = 0; j < 4; j++)
      attn[(size_t)(rowbase + r0 + i) * 1024 + h * 64 + c0 + j] = f2bf(o[i][j]);
}

// ---------------------------------------------------------------------------
// In-place fp32 LayerNorm
// ---------------------------------------------------------------------------
__global__ __launch_bounds__(256) void ln_inplace(
    float* __restrict__ y, const float* __restrict__ gamma,
    const float* __restrict__ beta) {
  const int row = blockIdx.x;
  const int t = threadIdx.x;
  float* yr = y + (size_t)row * 1024;
  float4 v = *(const float4*)(yr + t * 4);
  float s1 = v.x + v.y + v.z + v.w;
  float s2 = v.x * v.x + v.y * v.y + v.z * v.z + v.w * v.w;
#pragma unroll
  for (int off = 32; off > 0; off >>= 1) {
    s1 += __shfl_down(s1, off);
    s2 += __shfl_down(s2, off);
  }
  __shared__ float red[8];
  const int lane = t & 63, wave = t >> 6;
  if (lane == 0) {
    red[wave] = s1;
    red[4 + wave] = s2;
  }
  __syncthreads();
  if (t == 0) {
    red[0] = red[0] + red[1] + red[2] + red[3];
    red[4] = red[4] + red[5] + red[6] + red[7];
  }
  __syncthreads();
  const float mean = red[0] * (1.0f / 1024.0f);
  const float var = red[4] * (1.0f / 1024.0f) - mean * mean;
  const float rstd = rsqrtf(var + 1e-5f);
  float4 g = *(const float4*)(gamma + t * 4);
  float4 bt = *(const float4*)(beta + t * 4);
  float4 o;
  o.x = (v.x - mean) * rstd * g.x + bt.x;
  o.y = (v.y - mean) * rstd * g.y + bt.y;
  o.z = (v.z - mean) * rstd * g.z + bt.z;
  o.w = (v.w - mean) * rstd * g.w + bt.w;
  *(float4*)(yr + t * 4) = o;
}

// ---------------------------------------------------------------------------
extern "C" void kernel_launch(void* const* d_in, const int* in_sizes, int n_in,
                              void* d_out, int out_size, void* d_ws,
                              size_t ws_size, hipStream_t stream) {
  const float* x = (const float*)d_in[0];
  const float* Wqkv = (const float*)d_in[1];
  const float* bqkv = (const float*)d_in[2];
  const float* Wproj = (const float*)d_in[3];
  const float* bproj = (const float*)d_in[4];
  const float* gamma = (const float*)d_in[5];
  const float* beta = (const float*)d_in[6];
  float* out = (float*)d_out;

  us* qkv = (us*)d_ws;                        // 16384*3072 (100.7 MB)
  us* attn = qkv + (size_t)16384 * 3072;      // 16384*1024 (33.6 MB)
  us* xb = attn + (size_t)16384 * 1024;       // 16384*1024 (33.6 MB)
  us* Wqkvb = xb + (size_t)16384 * 1024;      // 3072*1024  (6.3 MB)
  us* Wprojb = Wqkvb + (size_t)3072 * 1024;   // 1024*1024  (2.1 MB)
  const size_t need =
      ((size_t)16384 * 3072 + 3 * (size_t)16384 * 1024 + (size_t)3072 * 1024 +
       (size_t)1024 * 1024) * sizeof(us);

  if (ws_size >= need) {
    cast_bf16<<<(16384 * 1024 / 8 + 255) / 256, 256, 0, stream>>>(x, xb,
                                                                  16384 * 128);
    cast_bf16<<<(3072 * 1024 / 8 + 255) / 256, 256, 0, stream>>>(Wqkv, Wqkvb,
                                                                 3072 * 128);
    cast_bf16<<<(1024 * 1024 / 8 + 255) / 256, 256, 0, stream>>>(Wproj, Wprojb,
                                                                 1024 * 128);
    gemm128<3072, 1024, 0, 1, us><<<dim3(24, 128), 256, 0, stream>>>(
        xb, Wqkvb, bqkv, nullptr, qkv);
    attn_mfma<<<1024, 256, 0, stream>>>(qkv, attn);
    gemm128<1024, 1024, 1, 0, float><<<dim3(8, 128), 256, 0, stream>>>(
        attn, Wprojb, bproj, x, out);
  } else {
    gemm_bt<3072, 1024, 0, float, us><<<dim3(24, 128), 256, 0, stream>>>(
        x, Wqkv, bqkv, nullptr, qkv);
    attn_win<<<4096, 256, 0, stream>>>(qkv, attn);
    gemm_bt<1024, 1024, 1, us, float><<<dim3(8, 128), 256, 0, stream>>>(
        attn, Wproj, bproj, x, out);
  }
  ln_inplace<<<16384, 256, 0, stream>>>(out, gamma, beta);
}

// Round 5
// 426.088 us; speedup vs baseline: 1.0002x; 1.0002x over previous
//
#include <hip/hip_runtime.h>
#include <stdint.h>

// LocalAttention: y = LN(x + proj(attn(qkv(x)))). fp32 inputs, fp32 output.
// B=4 L=4096 D=1024 H=16 W=HD=64 -> M=16384 rows.
//
// R12: fix the BK=32 LDS swizzle. R11 measured 1.26e7 bank-conflict cycles:
// slot = (r&1)*4 + (g^(r&3)) collides within consecutive-8-lane read groups
// (lanes 0-7 hit slots {0,5,2,7,0,5,2,7}). Correct bijection:
//   sigma(r,g) = (r&1)*4 + (g ^ ((r>>1)&3))
// -> read phys group = lq ^ ((lr>>1)&3), distinct across every 8-lane group
// (verified for all four groups). DMA dest stays flat; source col pre-swizzle
// = (tid&3) ^ ((tid>>3)&3) (still whole-64B-row coalesced segments).
// Everything else identical to R11 (128x128 tile, BK=32, 2-barrier K-loop,
// counted vmcnt(4) prefetch, XCD-bijective block swizzle, 3 blocks/CU,
// head-major QKV layout, 4-window attn blocks).

typedef __attribute__((ext_vector_type(8))) short short8;
typedef __attribute__((ext_vector_type(4))) float float4v;
typedef unsigned short us;

#define GAS const __attribute__((address_space(1))) void
#define LAS __attribute__((address_space(3))) void

__device__ __forceinline__ float bf2f(us u) {
  return __uint_as_float(((unsigned int)u) << 16);
}
__device__ __forceinline__ us f2bf(float f) {
  unsigned int u = __float_as_uint(f);
  unsigned int r = u + 0x7FFFu + ((u >> 16) & 1u);
  return (us)(r >> 16);
}
__device__ __forceinline__ int4 stage8(const float* p) {
  float4 a = *(const float4*)p;
  float4 b = *(const float4*)(p + 4);
  int4 r;
  us* u = (us*)&r;
  u[0] = f2bf(a.x); u[1] = f2bf(a.y); u[2] = f2bf(a.z); u[3] = f2bf(a.w);
  u[4] = f2bf(b.x); u[5] = f2bf(b.y); u[6] = f2bf(b.z); u[7] = f2bf(b.w);
  return r;
}
__device__ __forceinline__ int4 stage8(const us* p) { return *(const int4*)p; }
__device__ __forceinline__ void stc(us* p, float v) { *p = f2bf(v); }
__device__ __forceinline__ void stc(float* p, float v) { *p = v; }

// ---------------------------------------------------------------------------
// fp32 -> bf16 precast, 8 elems/thread
// ---------------------------------------------------------------------------
__global__ __launch_bounds__(256) void cast_bf16(const float* __restrict__ src,
                                                 us* __restrict__ dst, int n8) {
  const int i = blockIdx.x * 256 + threadIdx.x;
  if (i < n8) *(int4*)(dst + (size_t)i * 8) = stage8(src + (size_t)i * 8);
}

// ---------------------------------------------------------------------------
// 128x128 GEMM, BK=32, 4 waves (2x2, per-wave 64x64 = 64 acc regs).
// C = A @ Bt^T + bias (+resid). LDS: 2-deep double buffer, 32 KiB total
// -> 3 blocks/CU (reg-capped at 76 VGPR + 64 AGPR). K-loop per tile t:
//   B0 barrier -> all waves finished reading tile t-1 (its buffer free)
//   STAGE(t+1) -> 4 global_load_lds into buf[cur^1]
//   vmcnt(4)   -> tile t's 4 loads landed; t+1's stay in flight
//   B1 barrier -> tile t visible to all waves
//   compute    -> 8 ds_read_b128 + 16 MFMA, no barriers
// Swizzle: logical (row r, 16B-group g) at phys slot (r&1)*4 + (g^((r>>1)&3))
// within the 128B bank window; staging pre-swizzles the SOURCE col so the
// flat lane-order DMA dest realizes it; reads XOR with (lr>>1)&3.
// XCD swizzle: (id&7)*(NWG/8)+(id>>3), NWG%8==0 (bijective).
// HM: head-major C store [mat][b*16+h][tok][d] for the QKV gemm.
// ---------------------------------------------------------------------------
template <int N, int K, int EPI, int HM, typename CT>
__global__ __launch_bounds__(256) void gemm128(
    const us* __restrict__ A, const us* __restrict__ Bt,
    const float* __restrict__ bias, const float* __restrict__ resid,
    CT* __restrict__ C) {
  constexpr int NBX = N / 128;
  constexpr int NBY = 128;  // 16384/128
  constexpr int NWG = NBX * NBY;
  __shared__ __align__(16) us As[2][128 * 32];
  __shared__ __align__(16) us Bs[2][128 * 32];
  const int tid = threadIdx.x;
  const int lane = tid & 63;
  const int wave = tid >> 6;
  const int wm = wave >> 1, wn = wave & 1;
  const int lr = lane & 15, lq = lane >> 4;

  int id = blockIdx.y * NBX + blockIdx.x;
  id = (id & 7) * (NWG / 8) + (id >> 3);  // XCD-contiguous tile ranges
  const int m0 = (id / NBX) * 128;
  const int n0 = (id % NBX) * 128;

  const int srow = tid >> 2;  // 0..63 (row within pass)
  // source col group: (tid&3) ^ ((tid>>3)&3)  [inverse of read-side swizzle]
  const int scol = (((tid & 3) ^ ((tid >> 3) & 3)) * 8);
  const int rg = (lr >> 1) & 3;  // read-side XOR term

  constexpr int NT = K / 32;

  float4v acc[4][4];
#pragma unroll
  for (int i = 0; i < 4; i++)
#pragma unroll
    for (int j = 0; j < 4; j++) acc[i][j] = (float4v)0.0f;

#define STG128(buf, t)                                                         \
  do {                                                                         \
    const size_t kof = (size_t)(t) * 32;                                       \
    _Pragma("unroll") for (int p = 0; p < 2; p++) {                            \
      const us* ga = A + (size_t)(m0 + p * 64 + srow) * K + kof + scol;        \
      __builtin_amdgcn_global_load_lds((GAS*)ga,                               \
          (LAS*)&As[buf][(p * 256 + tid) * 8], 16, 0, 0);                      \
    }                                                                          \
    _Pragma("unroll") for (int p = 0; p < 2; p++) {                            \
      const us* gb = Bt + (size_t)(n0 + p * 64 + srow) * K + kof + scol;       \
      __builtin_amdgcn_global_load_lds((GAS*)gb,                               \
          (LAS*)&Bs[buf][(p * 256 + tid) * 8], 16, 0, 0);                      \
    }                                                                          \
  } while (0)

  STG128(0, 0);  // prologue: tile 0 in flight

  for (int t = 0; t < NT; t++) {
    const int cur = t & 1;
    __builtin_amdgcn_s_barrier();  // B0: tile t-1 reads complete everywhere
    if (t + 1 < NT) {
      STG128(cur ^ 1, t + 1);      // overwrite t-1's buffer (safe after B0)
      asm volatile("s_waitcnt vmcnt(4)" ::: "memory");  // tile t landed
    } else {
      asm volatile("s_waitcnt vmcnt(0)" ::: "memory");  // drain last tile
    }
    __builtin_amdgcn_s_barrier();  // B1: tile t visible to all waves

    const us* Ab = As[cur];
    const us* Bb = Bs[cur];
    short8 af[4], bf8[4];
#pragma unroll
    for (int mt = 0; mt < 4; mt++)
      af[mt] = *(const short8*)&Ab[(wm * 64 + mt * 16 + lr) * 32 +
                                   ((lq ^ rg) * 8)];
#pragma unroll
    for (int nt = 0; nt < 4; nt++)
      bf8[nt] = *(const short8*)&Bb[(wn * 64 + nt * 16 + lr) * 32 +
                                    ((lq ^ rg) * 8)];
    __builtin_amdgcn_s_setprio(1);
#pragma unroll
    for (int mt = 0; mt < 4; mt++)
#pragma unroll
      for (int nt = 0; nt < 4; nt++)
        acc[mt][nt] = __builtin_amdgcn_mfma_f32_16x16x32_bf16(
            af[mt], bf8[nt], acc[mt][nt], 0, 0, 0);
    __builtin_amdgcn_s_setprio(0);
  }
#undef STG128

  float bb[4];
#pragma unroll
  for (int nt = 0; nt < 4; nt++) bb[nt] = bias[n0 + wn * 64 + nt * 16 + lr];
#pragma unroll
  for (int mt = 0; mt < 4; mt++) {
    const int rbase = m0 + wm * 64 + mt * 16 + lq * 4;
#pragma unroll
    for (int nt = 0; nt < 4; nt++) {
      const int col = n0 + wn * 64 + nt * 16 + lr;
#pragma unroll
      for (int r = 0; r < 4; r++) {
        float v = acc[mt][nt][r] + bb[nt];
        const int row = rbase + r;
        size_t idx;
        if (HM) {
          // head-major: [mat][b*16+h][tok][d]
          const int mat = col >> 10, hh = (col >> 6) & 15, d = col & 63;
          idx = (size_t)mat * (16384u * 1024u) +
                (size_t)((row >> 12) * 16 + hh) * (4096u * 64u) +
                (size_t)(row & 4095) * 64 + d;
        } else {
          idx = (size_t)row * N + col;
        }
        if (EPI) v += resid[idx];
        stc(&C[idx], v);
      }
    }
  }
}

// ---------------------------------------------------------------------------
// MFMA windowed attention, head-major input, 4 windows per block.
// One block (4 waves) processes windows g0..g0+3 of the same (b,h)
// sequentially. Per window: stage V^T (cross-wave) -> S=QK^T from global
// (L1-local contiguous 8KB tiles) -> in-register softmax -> P to per-wave
// LDS -> barrier (Vt ready) -> O=PV -> store -> barrier (Vt reads done,
// next window may overwrite). P is per-wave-private (no sync needed).
// ---------------------------------------------------------------------------
__global__ __launch_bounds__(256) void attn_mfma(
    const us* __restrict__ qkv, us* __restrict__ attn) {
  __shared__ __align__(16) us Vt[64 * 64];       // elem(d,j) at d*64+((j>>3)^(d&7))*8+(j&7)
  __shared__ __align__(16) us Pl[4 * 16 * 64];   // per-wave 16x64, same swizzle
  const int g0 = blockIdx.x * 4;
  const int h = (g0 >> 6) & 15;   // constant over the 4 windows (4 | 64)
  const int b = g0 >> 10;
  const int tid = threadIdx.x;
  const int lane = tid & 63;
  const int w = tid >> 6;
  const int lr = lane & 15, lq = lane >> 4;

  const us* Qh = qkv + (size_t)(b * 16 + h) * (4096u * 64u);
  const us* Kh = Qh + (size_t)16384 * 1024;
  const us* Vh = Kh + (size_t)16384 * 1024;

  for (int i = 0; i < 4; i++) {
    const int wi = (g0 + i) & 63;
    const int rowbase = b * 4096 + wi * 64;
    const us* Qb = Qh + (size_t)wi * 4096;
    const us* Kb = Kh + (size_t)wi * 4096;
    const us* Vb = Vh + (size_t)wi * 4096;

    // ---- stage V^T (swizzled): wave w covers d in [16w,16w+16)
    {
      const int r = lane;  // token in window
      const int cs = w * 16;
      const us* vsrc = Vb + (size_t)r * 64 + cs;
      int4 v0 = *(const int4*)vsrc;
      int4 v1 = *(const int4*)(vsrc + 8);
      const us* vv0 = (const us*)&v0;
      const us* vv1 = (const us*)&v1;
#pragma unroll
      for (int k = 0; k < 8; k++) {
        const int d = cs + k;
        Vt[d * 64 + (((r >> 3) ^ (d & 7)) * 8) + (r & 7)] = vv0[k];
      }
#pragma unroll
      for (int k = 0; k < 8; k++) {
        const int d = cs + 8 + k;
        Vt[d * 64 + (((r >> 3) ^ (d & 7)) * 8) + (r & 7)] = vv1[k];
      }
    }

    // ---- S = Q K^T (rows 16w..16w+15), frags from global (L1-local)
    short8 aq[2];
    {
      const us* qrow = Qb + (size_t)(w * 16 + lr) * 64 + lq * 8;
      aq[0] = *(const short8*)qrow;
      aq[1] = *(const short8*)(qrow + 32);
    }
    float4v s[4];
#pragma unroll
    for (int nt = 0; nt < 4; nt++) s[nt] = (float4v)0.0f;
#pragma unroll
    for (int kk8 = 0; kk8 < 2; kk8++) {
#pragma unroll
      for (int nt = 0; nt < 4; nt++) {
        const us* krow = Kb + (size_t)(nt * 16 + lr) * 64 + kk8 * 32 + lq * 8;
        short8 bk = *(const short8*)krow;
        s[nt] = __builtin_amdgcn_mfma_f32_16x16x32_bf16(aq[kk8], bk, s[nt], 0, 0, 0);
      }
    }

    // ---- softmax per row
    float p[4][4];  // [nt][r]
#pragma unroll
    for (int r = 0; r < 4; r++) {
      float mx = -1e30f;
#pragma unroll
      for (int nt = 0; nt < 4; nt++) {
        s[nt][r] *= 0.125f;
        mx = fmaxf(mx, s[nt][r]);
      }
      mx = fmaxf(mx, __shfl_xor(mx, 1));
      mx = fmaxf(mx, __shfl_xor(mx, 2));
      mx = fmaxf(mx, __shfl_xor(mx, 4));
      mx = fmaxf(mx, __shfl_xor(mx, 8));
      float sum = 0.f;
#pragma unroll
      for (int nt = 0; nt < 4; nt++) {
        p[nt][r] = __expf(s[nt][r] - mx);
        sum += p[nt][r];
      }
      sum += __shfl_xor(sum, 1);
      sum += __shfl_xor(sum, 2);
      sum += __shfl_xor(sum, 4);
      sum += __shfl_xor(sum, 8);
      const float inv = 1.0f / sum;
#pragma unroll
      for (int nt = 0; nt < 4; nt++) p[nt][r] *= inv;
    }

    // ---- P -> LDS (per-wave region, swizzled), C-layout source
    us* pw = Pl + w * 1024;
#pragma unroll
    for (int nt = 0; nt < 4; nt++) {
      const int c = nt * 16 + lr;
#pragma unroll
      for (int r = 0; r < 4; r++) {
        const int row = lq * 4 + r;
        pw[row * 64 + (((c >> 3) ^ (row & 7)) * 8) + (c & 7)] = f2bf(p[nt][r]);
      }
    }
    __syncthreads();  // Vt (cross-wave) staged; P (own-wave) ordered by lgkm

    // ---- O = P V  (A-frag from Pl, B-frag from Vt)
    float4v o[4];
#pragma unroll
    for (int nt = 0; nt < 4; nt++) o[nt] = (float4v)0.0f;
#pragma unroll
    for (int kk8 = 0; kk8 < 2; kk8++) {
      short8 pa = *(const short8*)&pw[lr * 64 + (((lq + kk8 * 4) ^ (lr & 7)) * 8)];
#pragma unroll
      for (int nt = 0; nt < 4; nt++) {
        const int d = nt * 16 + lr;
        short8 vb = *(const short8*)&Vt[d * 64 + (((lq + kk8 * 4) ^ (d & 7)) * 8)];
        o[nt] = __builtin_amdgcn_mfma_f32_16x16x32_bf16(pa, vb, o[nt], 0, 0, 0);
      }
    }

    // ---- store O (C-layout): row = 16w+lq*4+r, col d = nt*16+lr
#pragma unroll
    for (int nt = 0; nt < 4; nt++) {
      const int d = nt * 16 + lr;
#pragma unroll
      for (int r = 0; r < 4; r++) {
        const int tok = rowbase + w * 16 + lq * 4 + r;
        attn[(size_t)tok * 1024 + h * 64 + d] = f2bf(o[nt][r]);
      }
    }
    if (i < 3) __syncthreads();  // Vt reads done before next window's writes
  }
}

// ---------------------------------------------------------------------------
// FALLBACK GEMM (R5-proven, VGPR staging + convert, unswizzled)
// ---------------------------------------------------------------------------
template <int N, int K, int EPI, typename AT, typename CT>
__global__ __launch_bounds__(256) void gemm_bt(
    const AT* __restrict__ A, const float* __restrict__ Bt,
    const float* __restrict__ bias, const float* __restrict__ resid,
    CT* __restrict__ C) {
  __shared__ __align__(16) us As[128 * 64];
  __shared__ __align__(16) us Bs[128 * 64];
  const int tid = threadIdx.x;
  const int lane = tid & 63;
  const int wave = tid >> 6;
  const int wm = wave >> 1, wn = wave & 1;
  const int lr = lane & 15, lq = lane >> 4;
  const int m0 = blockIdx.y * 128;
  const int n0 = blockIdx.x * 128;
  const int trow = tid >> 3;
  const int tcol = (tid & 7) * 8;

  float4v acc[4][4];
#pragma unroll
  for (int i = 0; i < 4; i++)
#pragma unroll
    for (int j = 0; j < 4; j++) acc[i][j] = (float4v)0.0f;

  for (int k0 = 0; k0 < K; k0 += 64) {
    int4 av[4], bv[4];
#pragma unroll
    for (int p = 0; p < 4; p++) {
      av[p] = stage8(A + (size_t)(m0 + p * 32 + trow) * K + k0 + tcol);
      bv[p] = stage8(Bt + (size_t)(n0 + p * 32 + trow) * K + k0 + tcol);
    }
#pragma unroll
    for (int p = 0; p < 4; p++) {
      *(int4*)&As[(p * 256 + tid) * 8] = av[p];
      *(int4*)&Bs[(p * 256 + tid) * 8] = bv[p];
    }
    __syncthreads();
#pragma unroll
    for (int kk = 0; kk < 64; kk += 32) {
      short8 af[4], bfv[4];
#pragma unroll
      for (int mt = 0; mt < 4; mt++)
        af[mt] = *(const short8*)&As[(wm * 64 + mt * 16 + lr) * 64 + kk + lq * 8];
#pragma unroll
      for (int nt = 0; nt < 4; nt++)
        bfv[nt] = *(const short8*)&Bs[(wn * 64 + nt * 16 + lr) * 64 + kk + lq * 8];
#pragma unroll
      for (int mt = 0; mt < 4; mt++)
#pragma unroll
        for (int nt = 0; nt < 4; nt++)
          acc[mt][nt] = __builtin_amdgcn_mfma_f32_16x16x32_bf16(
              af[mt], bfv[nt], acc[mt][nt], 0, 0, 0);
    }
    __syncthreads();
  }

  float bb[4];
#pragma unroll
  for (int nt = 0; nt < 4; nt++) bb[nt] = bias[n0 + wn * 64 + nt * 16 + lr];
#pragma unroll
  for (int mt = 0; mt < 4; mt++) {
    const int rbase = m0 + wm * 64 + mt * 16 + lq * 4;
#pragma unroll
    for (int nt = 0; nt < 4; nt++) {
      const int col = n0 + wn * 64 + nt * 16 + lr;
#pragma unroll
      for (int r = 0; r < 4; r++) {
        float v = acc[mt][nt][r] + bb[nt];
        size_t idx = (size_t)(rbase + r) * N + col;
        if (EPI) v += resid[idx];
        stc(&C[idx], v);
      }
    }
  }
}

// ---------------------------------------------------------------------------
// Fallback VALU attention (R5-proven, row-major qkv)
// ---------------------------------------------------------------------------
__global__ __launch_bounds__(256) void attn_win(
    const us* __restrict__ qkv, us* __restrict__ attn) {
  __shared__ float qs[64][65];
  __shared__ float ks[64][65];
  __shared__ float vs[64][65];
  const int wid = blockIdx.x;
  const int wi = wid & 63;
  const int h = (wid >> 6) & 15;
  const int b = wid >> 10;
  const int t = threadIdx.x;
  const int rowbase = b * 4096 + wi * 64;
  {
    const int r = t >> 2;
    const int cs = (t & 3) * 16;
    const us* base = qkv + (size_t)(rowbase + r) * 3072 + h * 64 + cs;
#pragma unroll
    for (int s = 0; s < 3; s++) {
      float* dst = (s == 0) ? &qs[r][cs] : (s == 1) ? &ks[r][cs] : &vs[r][cs];
      const us* src = base + s * 1024;
#pragma unroll
      for (int half = 0; half < 2; half++) {
        int4 dv = *(const int4*)(src + half * 8);
        const us* tp = (const us*)&dv;
#pragma unroll
        for (int i = 0; i < 8; i++) dst[half * 8 + i] = bf2f(tp[i]);
      }
    }
  }
  __syncthreads();
  const int r0 = (t >> 4) * 4;
  const int c0 = (t & 15) * 4;
  float acc[4][4] = {};
#pragma unroll 8
  for (int k = 0; k < 64; k++) {
    float qv[4], kv[4];
#pragma unroll
    for (int i = 0; i < 4; i++) qv[i] = qs[r0 + i][k];
#pragma unroll
    for (int j = 0; j < 4; j++) kv[j] = ks[c0 + j][k];
#pragma unroll
    for (int i = 0; i < 4; i++)
#pragma unroll
      for (int j = 0; j < 4; j++) acc[i][j] += qv[i] * kv[j];
  }
  __syncthreads();
#pragma unroll
  for (int i = 0; i < 4; i++)
#pragma unroll
    for (int j = 0; j < 4; j++) qs[r0 + i][c0 + j] = acc[i][j] * 0.125f;
  __syncthreads();
  {
    const int rr = t >> 2;
    const int cs = (t & 3) * 16;
    float pv[16];
    float m = -1e30f;
#pragma unroll
    for (int i = 0; i < 16; i++) {
      pv[i] = qs[rr][cs + i];
      m = fmaxf(m, pv[i]);
    }
    m = fmaxf(m, __shfl_xor(m, 1));
    m = fmaxf(m, __shfl_xor(m, 2));
    float ssum = 0.f;
#pragma unroll
    for (int i = 0; i < 16; i++) {
      pv[i] = __expf(pv[i] - m);
      ssum += pv[i];
    }
    ssum += __shfl_xor(ssum, 1);
    ssum += __shfl_xor(ssum, 2);
    const float inv = 1.0f / ssum;
#pragma unroll
    for (int i = 0; i < 16; i++) qs[rr][cs + i] = pv[i] * inv;
  }
  __syncthreads();
  float o[4][4] = {};
#pragma unroll 8
  for (int k = 0; k < 64; k++) {
    float pr[4], vv[4];
#pragma unroll
    for (int i = 0; i < 4; i++) pr[i] = qs[r0 + i][k];
#pragma unroll
    for (int j = 0; j < 4; j++) vv[j] = vs[k][c0 + j];
#pragma unroll
    for (int i = 0; i < 4; i++)
#pragma unroll
      for (int j = 0; j < 4; j++) o[i][j] += pr[i] * vv[j];
  }
#pragma unroll
  for (int i = 0; i < 4; i++)
#pragma unroll
    for (int j = 0; j < 4; j++)
      attn[(size_t)(rowbase + r0 + i) * 1024 + h * 64 + c0 + j] = f2bf(o[i][j]);
}

// ---------------------------------------------------------------------------
// In-place fp32 LayerNorm
// ---------------------------------------------------------------------------
__global__ __launch_bounds__(256) void ln_inplace(
    float* __restrict__ y, const float* __restrict__ gamma,
    const float* __restrict__ beta) {
  const int row = blockIdx.x;
  const int t = threadIdx.x;
  float* yr = y + (size_t)row * 1024;
  float4 v = *(const float4*)(yr + t * 4);
  float s1 = v.x + v.y + v.z + v.w;
  float s2 = v.x * v.x + v.y * v.y + v.z * v.z + v.w * v.w;
#pragma unroll
  for (int off = 32; off > 0; off >>= 1) {
    s1 += __shfl_down(s1, off);
    s2 += __shfl_down(s2, off);
  }
  __shared__ float red[8];
  const int lane = t & 63, wave = t >> 6;
  if (lane == 0) {
    red[wave] = s1;
    red[4 + wave] = s2;
  }
  __syncthreads();
  if (t == 0) {
    red[0] = red[0] + red[1] + red[2] + red[3];
    red[4] = red[4] + red[5] + red[6] + red[7];
  }
  __syncthreads();
  const float mean = red[0] * (1.0f / 1024.0f);
  const float var = red[4] * (1.0f / 1024.0f) - mean * mean;
  const float rstd = rsqrtf(var + 1e-5f);
  float4 g = *(const float4*)(gamma + t * 4);
  float4 bt = *(const float4*)(beta + t * 4);
  float4 o;
  o.x = (v.x - mean) * rstd * g.x + bt.x;
  o.y = (v.y - mean) * rstd * g.y + bt.y;
  o.z = (v.z - mean) * rstd * g.z + bt.z;
  o.w = (v.w - mean) * rstd * g.w + bt.w;
  *(float4*)(yr + t * 4) = o;
}

// ---------------------------------------------------------------------------
extern "C" void kernel_launch(void* const* d_in, const int* in_sizes, int n_in,
                              void* d_out, int out_size, void* d_ws,
                              size_t ws_size, hipStream_t stream) {
  const float* x = (const float*)d_in[0];
  const float* Wqkv = (const float*)d_in[1];
  const float* bqkv = (const float*)d_in[2];
  const float* Wproj = (const float*)d_in[3];
  const float* bproj = (const float*)d_in[4];
  const float* gamma = (const float*)d_in[5];
  const float* beta = (const float*)d_in[6];
  float* out = (float*)d_out;

  us* qkv = (us*)d_ws;                        // 16384*3072 (100.7 MB)
  us* attn = qkv + (size_t)16384 * 3072;      // 16384*1024 (33.6 MB)
  us* xb = attn + (size_t)16384 * 1024;       // 16384*1024 (33.6 MB)
  us* Wqkvb = xb + (size_t)16384 * 1024;      // 3072*1024  (6.3 MB)
  us* Wprojb = Wqkvb + (size_t)3072 * 1024;   // 1024*1024  (2.1 MB)
  const size_t need =
      ((size_t)16384 * 3072 + 3 * (size_t)16384 * 1024 + (size_t)3072 * 1024 +
       (size_t)1024 * 1024) * sizeof(us);

  if (ws_size >= need) {
    cast_bf16<<<(16384 * 1024 / 8 + 255) / 256, 256, 0, stream>>>(x, xb,
                                                                  16384 * 128);
    cast_bf16<<<(3072 * 1024 / 8 + 255) / 256, 256, 0, stream>>>(Wqkv, Wqkvb,
                                                                 3072 * 128);
    cast_bf16<<<(1024 * 1024 / 8 + 255) / 256, 256, 0, stream>>>(Wproj, Wprojb,
                                                                 1024 * 128);
    gemm128<3072, 1024, 0, 1, us><<<dim3(24, 128), 256, 0, stream>>>(
        xb, Wqkvb, bqkv, nullptr, qkv);
    attn_mfma<<<1024, 256, 0, stream>>>(qkv, attn);
    gemm128<1024, 1024, 1, 0, float><<<dim3(8, 128), 256, 0, stream>>>(
        attn, Wprojb, bproj, x, out);
  } else {
    gemm_bt<3072, 1024, 0, float, us><<<dim3(24, 128), 256, 0, stream>>>(
        x, Wqkv, bqkv, nullptr, qkv);
    attn_win<<<4096, 256, 0, stream>>>(qkv, attn);
    gemm_bt<1024, 1024, 1, us, float><<<dim3(8, 128), 256, 0, stream>>>(
        attn, Wproj, bproj, x, out);
  }
  ln_inplace<<<16384, 256, 0, stream>>>(out, gamma, beta);
}

// Round 6
// 400.129 us; speedup vs baseline: 1.0651x; 1.0649x over previous
//
#include <hip/hip_runtime.h>
#include <stdint.h>

// LocalAttention: y = LN(x + proj(attn(qkv(x)))). fp32 inputs, fp32 output.
// B=4 L=4096 D=1024 H=16 W=HD=64 -> M=16384 rows.
//
// R13: best-of composition. R12 proved BK=32 structure is worse than BK=64
// even at 3 blocks/CU (145.8 vs 125 us, per-tile fixed costs doubled), and
// the R11 attn restructure (4 serial windows/block) correlates with the
// +50 us non-gemm regression. So:
//  - gemm1 (QKV): R9's gemm256 verbatim -- 256x256, BK=64, 2-barrier K-loop,
//    counted vmcnt(8) one-tile-ahead global_load_lds, XOR-8 swizzle
//    (measured: 125 us, MfmaUtil 34.6, conflicts 0), head-major epilogue.
//  - attn: R2's 1-window-per-block head-major attn_mfma verbatim (part of
//    both best totals; max TLP, no serialized window chains).
//  - gemm2 (proj): R12's gemm128 verbatim -- 128x128, BK=32, corrected
//    swizzle (0 conflicts), 3 blocks/CU, 1024 blocks (vs R2's 256-block
//    1/CU single-generation launch). This is the one substitution vs R2;
//    any total delta vs 354 us is attributable here.

typedef __attribute__((ext_vector_type(8))) short short8;
typedef __attribute__((ext_vector_type(4))) float float4v;
typedef unsigned short us;

#define GAS const __attribute__((address_space(1))) void
#define LAS __attribute__((address_space(3))) void

__device__ __forceinline__ float bf2f(us u) {
  return __uint_as_float(((unsigned int)u) << 16);
}
__device__ __forceinline__ us f2bf(float f) {
  unsigned int u = __float_as_uint(f);
  unsigned int r = u + 0x7FFFu + ((u >> 16) & 1u);
  return (us)(r >> 16);
}
__device__ __forceinline__ int4 stage8(const float* p) {
  float4 a = *(const float4*)p;
  float4 b = *(const float4*)(p + 4);
  int4 r;
  us* u = (us*)&r;
  u[0] = f2bf(a.x); u[1] = f2bf(a.y); u[2] = f2bf(a.z); u[3] = f2bf(a.w);
  u[4] = f2bf(b.x); u[5] = f2bf(b.y); u[6] = f2bf(b.z); u[7] = f2bf(b.w);
  return r;
}
__device__ __forceinline__ int4 stage8(const us* p) { return *(const int4*)p; }
__device__ __forceinline__ void stc(us* p, float v) { *p = f2bf(v); }
__device__ __forceinline__ void stc(float* p, float v) { *p = v; }

// ---------------------------------------------------------------------------
// fp32 -> bf16 precast, 8 elems/thread
// ---------------------------------------------------------------------------
__global__ __launch_bounds__(256) void cast_bf16(const float* __restrict__ src,
                                                 us* __restrict__ dst, int n8) {
  const int i = blockIdx.x * 256 + threadIdx.x;
  if (i < n8) *(int4*)(dst + (size_t)i * 8) = stage8(src + (size_t)i * 8);
}

// ---------------------------------------------------------------------------
// 256x256 GEMM, BK=64, 2-barrier K-loop + counted vmcnt prefetch (R9-proven:
// 125 us QKV, MfmaUtil 34.6, conflicts 0). 512 threads = 8 waves (2M x 4N),
// per-wave 128x64 output. LDS: 2-deep double buffer, 128 KiB (1 block/CU).
// K-loop per tile t:
//   B0 barrier -> all waves finished reading tile t-1 (its buffer is free)
//   STAGE(t+1) -> 8 global_load_lds into buf[cur^1] (safe after B0)
//   vmcnt(8)   -> tile t's 8 loads landed; t+1's stay in flight
//   B1 barrier -> tile t visible to all waves
//   compute    -> 24 ds_read_b128 + 64 MFMA, NO barriers (waves drift)
// Swizzle: logical col-group g of row r stored at phys group g^(r&7);
// staging pre-swizzles the SOURCE col; fragment reads apply the same XOR.
// HM: head-major C store [mat][b*16+h][tok][d] for the QKV gemm.
// ---------------------------------------------------------------------------
template <int N, int K, int EPI, int HM, typename CT>
__global__ __launch_bounds__(512, 1) void gemm256(
    const us* __restrict__ A, const us* __restrict__ Bt,
    const float* __restrict__ bias, const float* __restrict__ resid,
    CT* __restrict__ C) {
  __shared__ __align__(16) us As[2][256 * 64];
  __shared__ __align__(16) us Bs[2][256 * 64];
  const int tid = threadIdx.x;
  const int lane = tid & 63;
  const int wave = tid >> 6;   // 0..7
  const int wm = wave >> 2;    // 0..1  (M half)
  const int wn = wave & 3;     // 0..3  (N quarter)
  const int lr = lane & 15, lq = lane >> 4;
  const int m0 = blockIdx.y * 256;
  const int n0 = blockIdx.x * 256;
  const int trow = tid >> 3;                        // 0..63 (row within 64-row pass)
  const int tcol = (((tid & 7) ^ (trow & 7)) * 8);  // XOR-swizzled src col

  constexpr int NT = K / 64;

  float4v acc[8][4];
#pragma unroll
  for (int i = 0; i < 8; i++)
#pragma unroll
    for (int j = 0; j < 4; j++) acc[i][j] = (float4v)0.0f;

#define STAGE256(buf, t)                                                       \
  do {                                                                         \
    const size_t kof = (size_t)(t) * 64;                                       \
    _Pragma("unroll") for (int q = 0; q < 4; q++) {                            \
      const us* ga = A + (size_t)(m0 + q * 64 + trow) * K + kof + tcol;        \
      __builtin_amdgcn_global_load_lds((GAS*)ga,                               \
          (LAS*)&As[buf][(q * 512 + tid) * 8], 16, 0, 0);                      \
    }                                                                          \
    _Pragma("unroll") for (int q = 0; q < 4; q++) {                            \
      const us* gb = Bt + (size_t)(n0 + q * 64 + trow) * K + kof + tcol;       \
      __builtin_amdgcn_global_load_lds((GAS*)gb,                               \
          (LAS*)&Bs[buf][(q * 512 + tid) * 8], 16, 0, 0);                      \
    }                                                                          \
  } while (0)

  STAGE256(0, 0);  // prologue: tile 0 in flight

  for (int t = 0; t < NT; t++) {
    const int cur = t & 1;
    __builtin_amdgcn_s_barrier();  // B0: tile t-1 reads complete everywhere
    if (t + 1 < NT) {
      STAGE256(cur ^ 1, t + 1);    // overwrite t-1's buffer (safe after B0)
      asm volatile("s_waitcnt vmcnt(8)" ::: "memory");  // tile t landed
    } else {
      asm volatile("s_waitcnt vmcnt(0)" ::: "memory");  // drain last tile
    }
    __builtin_amdgcn_s_barrier();  // B1: tile t visible to all waves

    const us* Ab = As[cur];
    const us* Bb = Bs[cur];
#pragma unroll
    for (int kk8 = 0; kk8 < 2; kk8++) {
      short8 bf8[4];
#pragma unroll
      for (int nt = 0; nt < 4; nt++) {
        const int row = wn * 64 + nt * 16 + lr;
        bf8[nt] = *(const short8*)&Bb[row * 64 + (((kk8 * 4 + lq) ^ (lr & 7)) * 8)];
      }
#pragma unroll
      for (int mh = 0; mh < 2; mh++) {
        short8 af[4];
#pragma unroll
        for (int mt = 0; mt < 4; mt++) {
          const int row = wm * 128 + mh * 64 + mt * 16 + lr;
          af[mt] = *(const short8*)&Ab[row * 64 + (((kk8 * 4 + lq) ^ (lr & 7)) * 8)];
        }
        __builtin_amdgcn_s_setprio(1);
#pragma unroll
        for (int mt = 0; mt < 4; mt++)
#pragma unroll
          for (int nt = 0; nt < 4; nt++)
            acc[mh * 4 + mt][nt] = __builtin_amdgcn_mfma_f32_16x16x32_bf16(
                af[mt], bf8[nt], acc[mh * 4 + mt][nt], 0, 0, 0);
        __builtin_amdgcn_s_setprio(0);
      }
    }
  }
#undef STAGE256

  float bb[4];
#pragma unroll
  for (int nt = 0; nt < 4; nt++) bb[nt] = bias[n0 + wn * 64 + nt * 16 + lr];
#pragma unroll
  for (int mh = 0; mh < 2; mh++)
#pragma unroll
    for (int mt = 0; mt < 4; mt++) {
      const int rbase = m0 + wm * 128 + mh * 64 + mt * 16 + lq * 4;
#pragma unroll
      for (int nt = 0; nt < 4; nt++) {
        const int col = n0 + wn * 64 + nt * 16 + lr;
#pragma unroll
        for (int r = 0; r < 4; r++) {
          float v = acc[mh * 4 + mt][nt][r] + bb[nt];
          const int row = rbase + r;
          size_t idx;
          if (HM) {
            // head-major: [mat][b*16+h][tok][d]
            const int mat = col >> 10, hh = (col >> 6) & 15, d = col & 63;
            idx = (size_t)mat * (16384u * 1024u) +
                  (size_t)((row >> 12) * 16 + hh) * (4096u * 64u) +
                  (size_t)(row & 4095) * 64 + d;
          } else {
            idx = (size_t)row * N + col;
          }
          if (EPI) v += resid[idx];
          stc(&C[idx], v);
        }
      }
    }
}

// ---------------------------------------------------------------------------
// 128x128 GEMM, BK=32, 4 waves (2x2, per-wave 64x64). R12-proven swizzle
// (0 conflicts), 3 blocks/CU, counted vmcnt(4) prefetch, XCD-bijective
// block remap. Used for the proj gemm (1024 blocks -> multi-generation
// overlap vs 256-block 1/CU gemm256).
// ---------------------------------------------------------------------------
template <int N, int K, int EPI, int HM, typename CT>
__global__ __launch_bounds__(256) void gemm128(
    const us* __restrict__ A, const us* __restrict__ Bt,
    const float* __restrict__ bias, const float* __restrict__ resid,
    CT* __restrict__ C) {
  constexpr int NBX = N / 128;
  constexpr int NBY = 128;  // 16384/128
  constexpr int NWG = NBX * NBY;
  __shared__ __align__(16) us As[2][128 * 32];
  __shared__ __align__(16) us Bs[2][128 * 32];
  const int tid = threadIdx.x;
  const int lane = tid & 63;
  const int wave = tid >> 6;
  const int wm = wave >> 1, wn = wave & 1;
  const int lr = lane & 15, lq = lane >> 4;

  int id = blockIdx.y * NBX + blockIdx.x;
  id = (id & 7) * (NWG / 8) + (id >> 3);  // XCD-contiguous tile ranges
  const int m0 = (id / NBX) * 128;
  const int n0 = (id % NBX) * 128;

  const int srow = tid >> 2;  // 0..63 (row within pass)
  // source col group: (tid&3) ^ ((tid>>3)&3)  [inverse of read-side swizzle]
  const int scol = (((tid & 3) ^ ((tid >> 3) & 3)) * 8);
  const int rg = (lr >> 1) & 3;  // read-side XOR term

  constexpr int NT = K / 32;

  float4v acc[4][4];
#pragma unroll
  for (int i = 0; i < 4; i++)
#pragma unroll
    for (int j = 0; j < 4; j++) acc[i][j] = (float4v)0.0f;

#define STG128(buf, t)                                                         \
  do {                                                                         \
    const size_t kof = (size_t)(t) * 32;                                       \
    _Pragma("unroll") for (int p = 0; p < 2; p++) {                            \
      const us* ga = A + (size_t)(m0 + p * 64 + srow) * K + kof + scol;        \
      __builtin_amdgcn_global_load_lds((GAS*)ga,                               \
          (LAS*)&As[buf][(p * 256 + tid) * 8], 16, 0, 0);                      \
    }                                                                          \
    _Pragma("unroll") for (int p = 0; p < 2; p++) {                            \
      const us* gb = Bt + (size_t)(n0 + p * 64 + srow) * K + kof + scol;       \
      __builtin_amdgcn_global_load_lds((GAS*)gb,                               \
          (LAS*)&Bs[buf][(p * 256 + tid) * 8], 16, 0, 0);                      \
    }                                                                          \
  } while (0)

  STG128(0, 0);  // prologue: tile 0 in flight

  for (int t = 0; t < NT; t++) {
    const int cur = t & 1;
    __builtin_amdgcn_s_barrier();  // B0: tile t-1 reads complete everywhere
    if (t + 1 < NT) {
      STG128(cur ^ 1, t + 1);      // overwrite t-1's buffer (safe after B0)
      asm volatile("s_waitcnt vmcnt(4)" ::: "memory");  // tile t landed
    } else {
      asm volatile("s_waitcnt vmcnt(0)" ::: "memory");  // drain last tile
    }
    __builtin_amdgcn_s_barrier();  // B1: tile t visible to all waves

    const us* Ab = As[cur];
    const us* Bb = Bs[cur];
    short8 af[4], bf8[4];
#pragma unroll
    for (int mt = 0; mt < 4; mt++)
      af[mt] = *(const short8*)&Ab[(wm * 64 + mt * 16 + lr) * 32 +
                                   ((lq ^ rg) * 8)];
#pragma unroll
    for (int nt = 0; nt < 4; nt++)
      bf8[nt] = *(const short8*)&Bb[(wn * 64 + nt * 16 + lr) * 32 +
                                    ((lq ^ rg) * 8)];
    __builtin_amdgcn_s_setprio(1);
#pragma unroll
    for (int mt = 0; mt < 4; mt++)
#pragma unroll
      for (int nt = 0; nt < 4; nt++)
        acc[mt][nt] = __builtin_amdgcn_mfma_f32_16x16x32_bf16(
            af[mt], bf8[nt], acc[mt][nt], 0, 0, 0);
    __builtin_amdgcn_s_setprio(0);
  }
#undef STG128

  float bb[4];
#pragma unroll
  for (int nt = 0; nt < 4; nt++) bb[nt] = bias[n0 + wn * 64 + nt * 16 + lr];
#pragma unroll
  for (int mt = 0; mt < 4; mt++) {
    const int rbase = m0 + wm * 64 + mt * 16 + lq * 4;
#pragma unroll
    for (int nt = 0; nt < 4; nt++) {
      const int col = n0 + wn * 64 + nt * 16 + lr;
#pragma unroll
      for (int r = 0; r < 4; r++) {
        float v = acc[mt][nt][r] + bb[nt];
        const int row = rbase + r;
        size_t idx;
        if (HM) {
          const int mat = col >> 10, hh = (col >> 6) & 15, d = col & 63;
          idx = (size_t)mat * (16384u * 1024u) +
                (size_t)((row >> 12) * 16 + hh) * (4096u * 64u) +
                (size_t)(row & 4095) * 64 + d;
        } else {
          idx = (size_t)row * N + col;
        }
        if (EPI) v += resid[idx];
        stc(&C[idx], v);
      }
    }
  }
}

// ---------------------------------------------------------------------------
// MFMA windowed attention, head-major input, 1 window per block (R2-proven).
// Q/K/V for the window are contiguous 8 KB blocks -> L1-resident after
// first touch. Output stays [token][1024] for the proj gemm.
// ---------------------------------------------------------------------------
__global__ __launch_bounds__(256) void attn_mfma(
    const us* __restrict__ qkv, us* __restrict__ attn) {
  __shared__ __align__(16) us Vt[64 * 64];       // elem(d,j) at d*64+((j>>3)^(d&7))*8+(j&7)
  __shared__ __align__(16) us Pl[4 * 16 * 64];   // per-wave 16x64, same swizzle
  const int wid = blockIdx.x;
  const int wi = wid & 63;
  const int h = (wid >> 6) & 15;
  const int b = wid >> 10;
  const int tid = threadIdx.x;
  const int lane = tid & 63;
  const int w = tid >> 6;
  const int lr = lane & 15, lq = lane >> 4;
  const int rowbase = b * 4096 + wi * 64;

  // head-major window bases: contiguous 64x64 bf16 tiles
  const us* Qb = qkv + (size_t)(b * 16 + h) * (4096u * 64u) + (size_t)wi * 4096;
  const us* Kb = Qb + (size_t)16384 * 1024;
  const us* Vb = Kb + (size_t)16384 * 1024;

  // ---- stage V^T (swizzled): wave w covers d in [16w,16w+16) for all tokens
  {
    const int r = lane;  // token in window
    const int cs = w * 16;
    const us* vsrc = Vb + (size_t)r * 64 + cs;
    int4 v0 = *(const int4*)vsrc;
    int4 v1 = *(const int4*)(vsrc + 8);
    const us* vv0 = (const us*)&v0;
    const us* vv1 = (const us*)&v1;
#pragma unroll
    for (int i = 0; i < 8; i++) {
      const int d = cs + i;
      Vt[d * 64 + (((r >> 3) ^ (d & 7)) * 8) + (r & 7)] = vv0[i];
    }
#pragma unroll
    for (int i = 0; i < 8; i++) {
      const int d = cs + 8 + i;
      Vt[d * 64 + (((r >> 3) ^ (d & 7)) * 8) + (r & 7)] = vv1[i];
    }
  }

  // ---- S = Q K^T (rows 16w..16w+15), frags from global (L1-local)
  short8 aq[2];
  {
    const us* qrow = Qb + (size_t)(w * 16 + lr) * 64 + lq * 8;
    aq[0] = *(const short8*)qrow;
    aq[1] = *(const short8*)(qrow + 32);
  }
  float4v s[4];
#pragma unroll
  for (int nt = 0; nt < 4; nt++) s[nt] = (float4v)0.0f;
#pragma unroll
  for (int kk8 = 0; kk8 < 2; kk8++) {
#pragma unroll
    for (int nt = 0; nt < 4; nt++) {
      const us* krow = Kb + (size_t)(nt * 16 + lr) * 64 + kk8 * 32 + lq * 8;
      short8 bk = *(const short8*)krow;
      s[nt] = __builtin_amdgcn_mfma_f32_16x16x32_bf16(aq[kk8], bk, s[nt], 0, 0, 0);
    }
  }

  // ---- softmax per row
  float p[4][4];  // [nt][r]
#pragma unroll
  for (int r = 0; r < 4; r++) {
    float mx = -1e30f;
#pragma unroll
    for (int nt = 0; nt < 4; nt++) {
      s[nt][r] *= 0.125f;
      mx = fmaxf(mx, s[nt][r]);
    }
    mx = fmaxf(mx, __shfl_xor(mx, 1));
    mx = fmaxf(mx, __shfl_xor(mx, 2));
    mx = fmaxf(mx, __shfl_xor(mx, 4));
    mx = fmaxf(mx, __shfl_xor(mx, 8));
    float sum = 0.f;
#pragma unroll
    for (int nt = 0; nt < 4; nt++) {
      p[nt][r] = __expf(s[nt][r] - mx);
      sum += p[nt][r];
    }
    sum += __shfl_xor(sum, 1);
    sum += __shfl_xor(sum, 2);
    sum += __shfl_xor(sum, 4);
    sum += __shfl_xor(sum, 8);
    const float inv = 1.0f / sum;
#pragma unroll
    for (int nt = 0; nt < 4; nt++) p[nt][r] *= inv;
  }

  // ---- P -> LDS (per-wave region, swizzled), C-layout source
  us* pw = Pl + w * 1024;
#pragma unroll
  for (int nt = 0; nt < 4; nt++) {
    const int c = nt * 16 + lr;
#pragma unroll
    for (int r = 0; r < 4; r++) {
      const int row = lq * 4 + r;
      pw[row * 64 + (((c >> 3) ^ (row & 7)) * 8) + (c & 7)] = f2bf(p[nt][r]);
    }
  }
  __syncthreads();  // Vt (cross-wave) + P visible

  // ---- O = P V  (A-frag from Pl, B-frag from Vt)
  float4v o[4];
#pragma unroll
  for (int nt = 0; nt < 4; nt++) o[nt] = (float4v)0.0f;
#pragma unroll
  for (int kk8 = 0; kk8 < 2; kk8++) {
    short8 pa = *(const short8*)&pw[lr * 64 + (((lq + kk8 * 4) ^ (lr & 7)) * 8)];
#pragma unroll
    for (int nt = 0; nt < 4; nt++) {
      const int d = nt * 16 + lr;
      short8 vb = *(const short8*)&Vt[d * 64 + (((lq + kk8 * 4) ^ (d & 7)) * 8)];
      o[nt] = __builtin_amdgcn_mfma_f32_16x16x32_bf16(pa, vb, o[nt], 0, 0, 0);
    }
  }

  // ---- store O (C-layout): row = 16w+lq*4+r, col d = nt*16+lr
#pragma unroll
  for (int nt = 0; nt < 4; nt++) {
    const int d = nt * 16 + lr;
#pragma unroll
    for (int r = 0; r < 4; r++) {
      const int tok = rowbase + w * 16 + lq * 4 + r;
      attn[(size_t)tok * 1024 + h * 64 + d] = f2bf(o[nt][r]);
    }
  }
}

// ---------------------------------------------------------------------------
// FALLBACK GEMM (R5-proven, VGPR staging + convert, unswizzled)
// ---------------------------------------------------------------------------
template <int N, int K, int EPI, typename AT, typename CT>
__global__ __launch_bounds__(256) void gemm_bt(
    const AT* __restrict__ A, const float* __restrict__ Bt,
    const float* __restrict__ bias, const float* __restrict__ resid,
    CT* __restrict__ C) {
  __shared__ __align__(16) us As[128 * 64];
  __shared__ __align__(16) us Bs[128 * 64];
  const int tid = threadIdx.x;
  const int lane = tid & 63;
  const int wave = tid >> 6;
  const int wm = wave >> 1, wn = wave & 1;
  const int lr = lane & 15, lq = lane >> 4;
  const int m0 = blockIdx.y * 128;
  const int n0 = blockIdx.x * 128;
  const int trow = tid >> 3;
  const int tcol = (tid & 7) * 8;

  float4v acc[4][4];
#pragma unroll
  for (int i = 0; i < 4; i++)
#pragma unroll
    for (int j = 0; j < 4; j++) acc[i][j] = (float4v)0.0f;

  for (int k0 = 0; k0 < K; k0 += 64) {
    int4 av[4], bv[4];
#pragma unroll
    for (int p = 0; p < 4; p++) {
      av[p] = stage8(A + (size_t)(m0 + p * 32 + trow) * K + k0 + tcol);
      bv[p] = stage8(Bt + (size_t)(n0 + p * 32 + trow) * K + k0 + tcol);
    }
#pragma unroll
    for (int p = 0; p < 4; p++) {
      *(int4*)&As[(p * 256 + tid) * 8] = av[p];
      *(int4*)&Bs[(p * 256 + tid) * 8] = bv[p];
    }
    __syncthreads();
#pragma unroll
    for (int kk = 0; kk < 64; kk += 32) {
      short8 af[4], bfv[4];
#pragma unroll
      for (int mt = 0; mt < 4; mt++)
        af[mt] = *(const short8*)&As[(wm * 64 + mt * 16 + lr) * 64 + kk + lq * 8];
#pragma unroll
      for (int nt = 0; nt < 4; nt++)
        bfv[nt] = *(const short8*)&Bs[(wn * 64 + nt * 16 + lr) * 64 + kk + lq * 8];
#pragma unroll
      for (int mt = 0; mt < 4; mt++)
#pragma unroll
        for (int nt = 0; nt < 4; nt++)
          acc[mt][nt] = __builtin_amdgcn_mfma_f32_16x16x32_bf16(
              af[mt], bfv[nt], acc[mt][nt], 0, 0, 0);
    }
    __syncthreads();
  }

  float bb[4];
#pragma unroll
  for (int nt = 0; nt < 4; nt++) bb[nt] = bias[n0 + wn * 64 + nt * 16 + lr];
#pragma unroll
  for (int mt = 0; mt < 4; mt++) {
    const int rbase = m0 + wm * 64 + mt * 16 + lq * 4;
#pragma unroll
    for (int nt = 0; nt < 4; nt++) {
      const int col = n0 + wn * 64 + nt * 16 + lr;
#pragma unroll
      for (int r = 0; r < 4; r++) {
        float v = acc[mt][nt][r] + bb[nt];
        size_t idx = (size_t)(rbase + r) * N + col;
        if (EPI) v += resid[idx];
        stc(&C[idx], v);
      }
    }
  }
}

// ---------------------------------------------------------------------------
// Fallback VALU attention (R5-proven, row-major qkv)
// ---------------------------------------------------------------------------
__global__ __launch_bounds__(256) void attn_win(
    const us* __restrict__ qkv, us* __restrict__ attn) {
  __shared__ float qs[64][65];
  __shared__ float ks[64][65];
  __shared__ float vs[64][65];
  const int wid = blockIdx.x;
  const int wi = wid & 63;
  const int h = (wid >> 6) & 15;
  const int b = wid >> 10;
  const int t = threadIdx.x;
  const int rowbase = b * 4096 + wi * 64;
  {
    const int r = t >> 2;
    const int cs = (t & 3) * 16;
    const us* base = qkv + (size_t)(rowbase + r) * 3072 + h * 64 + cs;
#pragma unroll
    for (int s = 0; s < 3; s++) {
      float* dst = (s == 0) ? &qs[r][cs] : (s == 1) ? &ks[r][cs] : &vs[r][cs];
      const us* src = base + s * 1024;
#pragma unroll
      for (int half = 0; half < 2; half++) {
        int4 dv = *(const int4*)(src + half * 8);
        const us* tp = (const us*)&dv;
#pragma unroll
        for (int i = 0; i < 8; i++) dst[half * 8 + i] = bf2f(tp[i]);
      }
    }
  }
  __syncthreads();
  const int r0 = (t >> 4) * 4;
  const int c0 = (t & 15) * 4;
  float acc[4][4] = {};
#pragma unroll 8
  for (int k = 0; k < 64; k++) {
    float qv[4], kv[4];
#pragma unroll
    for (int i = 0; i < 4; i++) qv[i] = qs[r0 + i][k];
#pragma unroll
    for (int j = 0; j < 4; j++) kv[j] = ks[c0 + j][k];
#pragma unroll
    for (int i = 0; i < 4; i++)
#pragma unroll
      for (int j = 0; j < 4; j++) acc[i][j] += qv[i] * kv[j];
  }
  __syncthreads();
#pragma unroll
  for (int i = 0; i < 4; i++)
#pragma unroll
    for (int j = 0; j < 4; j++) qs[r0 + i][c0 + j] = acc[i][j] * 0.125f;
  __syncthreads();
  {
    const int rr = t >> 2;
    const int cs = (t & 3) * 16;
    float pv[16];
    float m = -1e30f;
#pragma unroll
    for (int i = 0; i < 16; i++) {
      pv[i] = qs[rr][cs + i];
      m = fmaxf(m, pv[i]);
    }
    m = fmaxf(m, __shfl_xor(m, 1));
    m = fmaxf(m, __shfl_xor(m, 2));
    float ssum = 0.f;
#pragma unroll
    for (int i = 0; i < 16; i++) {
      pv[i] = __expf(pv[i] - m);
      ssum += pv[i];
    }
    ssum += __shfl_xor(ssum, 1);
    ssum += __shfl_xor(ssum, 2);
    const float inv = 1.0f / ssum;
#pragma unroll
    for (int i = 0; i < 16; i++) qs[rr][cs + i] = pv[i] * inv;
  }
  __syncthreads();
  float o[4][4] = {};
#pragma unroll 8
  for (int k = 0; k < 64; k++) {
    float pr[4], vv[4];
#pragma unroll
    for (int i = 0; i < 4; i++) pr[i] = qs[r0 + i][k];
#pragma unroll
    for (int j = 0; j < 4; j++) vv[j] = vs[k][c0 + j];
#pragma unroll
    for (int i = 0; i < 4; i++)
#pragma unroll
      for (int j = 0; j < 4; j++) o[i][j] += pr[i] * vv[j];
  }
#pragma unroll
  for (int i = 0; i < 4; i++)
#pragma unroll
    for (int j = 0; j < 4; j++)
      attn[(size_t)(rowbase + r0 + i) * 1024 + h * 64 + c0 + j] = f2bf(o[i][j]);
}

// ---------------------------------------------------------------------------
// In-place fp32 LayerNorm
// ---------------------------------------------------------------------------
__global__ __launch_bounds__(256) void ln_inplace(
    float* __restrict__ y, const float* __restrict__ gamma,
    const float* __restrict__ beta) {
  const int row = blockIdx.x;
  const int t = threadIdx.x;
  float* yr = y + (size_t)row * 1024;
  float4 v = *(const float4*)(yr + t * 4);
  float s1 = v.x + v.y + v.z + v.w;
  float s2 = v.x * v.x + v.y * v.y + v.z * v.z + v.w * v.w;
#pragma unroll
  for (int off = 32; off > 0; off >>= 1) {
    s1 += __shfl_down(s1, off);
    s2 += __shfl_down(s2, off);
  }
  __shared__ float red[8];
  const int lane = t & 63, wave = t >> 6;
  if (lane == 0) {
    red[wave] = s1;
    red[4 + wave] = s2;
  }
  __syncthreads();
  if (t == 0) {
    red[0] = red[0] + red[1] + red[2] + red[3];
    red[4] = red[4] + red[5] + red[6] + red[7];
  }
  __syncthreads();
  const float mean = red[0] * (1.0f / 1024.0f);
  const float var = red[4] * (1.0f / 1024.0f) - mean * mean;
  const float rstd = rsqrtf(var + 1e-5f);
  float4 g = *(const float4*)(gamma + t * 4);
  float4 bt = *(const float4*)(beta + t * 4);
  float4 o;
  o.x = (v.x - mean) * rstd * g.x + bt.x;
  o.y = (v.y - mean) * rstd * g.y + bt.y;
  o.z = (v.z - mean) * rstd * g.z + bt.z;
  o.w = (v.w - mean) * rstd * g.w + bt.w;
  *(float4*)(yr + t * 4) = o;
}

// ---------------------------------------------------------------------------
extern "C" void kernel_launch(void* const* d_in, const int* in_sizes, int n_in,
                              void* d_out, int out_size, void* d_ws,
                              size_t ws_size, hipStream_t stream) {
  const float* x = (const float*)d_in[0];
  const float* Wqkv = (const float*)d_in[1];
  const float* bqkv = (const float*)d_in[2];
  const float* Wproj = (const float*)d_in[3];
  const float* bproj = (const float*)d_in[4];
  const float* gamma = (const float*)d_in[5];
  const float* beta = (const float*)d_in[6];
  float* out = (float*)d_out;

  us* qkv = (us*)d_ws;                        // 16384*3072 (100.7 MB)
  us* attn = qkv + (size_t)16384 * 3072;      // 16384*1024 (33.6 MB)
  us* xb = attn + (size_t)16384 * 1024;       // 16384*1024 (33.6 MB)
  us* Wqkvb = xb + (size_t)16384 * 1024;      // 3072*1024  (6.3 MB)
  us* Wprojb = Wqkvb + (size_t)3072 * 1024;   // 1024*1024  (2.1 MB)
  const size_t need =
      ((size_t)16384 * 3072 + 3 * (size_t)16384 * 1024 + (size_t)3072 * 1024 +
       (size_t)1024 * 1024) * sizeof(us);

  if (ws_size >= need) {
    cast_bf16<<<(16384 * 1024 / 8 + 255) / 256, 256, 0, stream>>>(x, xb,
                                                                  16384 * 128);
    cast_bf16<<<(3072 * 1024 / 8 + 255) / 256, 256, 0, stream>>>(Wqkv, Wqkvb,
                                                                 3072 * 128);
    cast_bf16<<<(1024 * 1024 / 8 + 255) / 256, 256, 0, stream>>>(Wproj, Wprojb,
                                                                 1024 * 128);
    gemm256<3072, 1024, 0, 1, us><<<dim3(12, 64), 512, 0, stream>>>(
        xb, Wqkvb, bqkv, nullptr, qkv);
    attn_mfma<<<4096, 256, 0, stream>>>(qkv, attn);
    gemm128<1024, 1024, 1, 0, float><<<dim3(8, 128), 256, 0, stream>>>(
        attn, Wprojb, bproj, x, out);
  } else {
    gemm_bt<3072, 1024, 0, float, us><<<dim3(24, 128), 256, 0, stream>>>(
        x, Wqkv, bqkv, nullptr, qkv);
    attn_win<<<4096, 256, 0, stream>>>(qkv, attn);
    gemm_bt<1024, 1024, 1, us, float><<<dim3(8, 128), 256, 0, stream>>>(
        attn, Wproj, bproj, x, out);
  }
  ln_inplace<<<16384, 256, 0, stream>>>(out, gamma, beta);
}

// Round 7
// 354.964 us; speedup vs baseline: 1.2006x; 1.1272x over previous
//
#include <hip/hip_runtime.h>
#include <stdint.h>

// LocalAttention: y = LN(x + proj(attn(qkv(x)))). fp32 inputs, fp32 output.
// B=4 L=4096 D=1024 H=16 W=HD=64 -> M=16384 rows.
//
// R14: restore the twice-proven R2/R9 composition + LN de-barrier.
// R13's attribution run showed gemm128-proj costs ~75-80 us vs gemm256-proj
// ~42 us (total 354->400 with only that swap + noise) -> proj goes back to
// gemm256<1024> (256 blocks, R2/R9-proven). gemm1 and attn unchanged
// (R9/R2-proven). LN: one WAVE per row (4 rows/block, 4096 blocks), pure
// shuffle reduction -- removes 2 __syncthreads + LDS round-trip per row vs
// ln_inplace's 16384 tiny blocks.
// Known budget (from R2 profile top-5 bound): casts ~20, gemm1 125-138,
// attn 90-124 (next target), gemm2 ~42, LN ~25->~20.

typedef __attribute__((ext_vector_type(8))) short short8;
typedef __attribute__((ext_vector_type(4))) float float4v;
typedef unsigned short us;

#define GAS const __attribute__((address_space(1))) void
#define LAS __attribute__((address_space(3))) void

__device__ __forceinline__ float bf2f(us u) {
  return __uint_as_float(((unsigned int)u) << 16);
}
__device__ __forceinline__ us f2bf(float f) {
  unsigned int u = __float_as_uint(f);
  unsigned int r = u + 0x7FFFu + ((u >> 16) & 1u);
  return (us)(r >> 16);
}
__device__ __forceinline__ int4 stage8(const float* p) {
  float4 a = *(const float4*)p;
  float4 b = *(const float4*)(p + 4);
  int4 r;
  us* u = (us*)&r;
  u[0] = f2bf(a.x); u[1] = f2bf(a.y); u[2] = f2bf(a.z); u[3] = f2bf(a.w);
  u[4] = f2bf(b.x); u[5] = f2bf(b.y); u[6] = f2bf(b.z); u[7] = f2bf(b.w);
  return r;
}
__device__ __forceinline__ int4 stage8(const us* p) { return *(const int4*)p; }
__device__ __forceinline__ void stc(us* p, float v) { *p = f2bf(v); }
__device__ __forceinline__ void stc(float* p, float v) { *p = v; }

// ---------------------------------------------------------------------------
// fp32 -> bf16 precast, 8 elems/thread
// ---------------------------------------------------------------------------
__global__ __launch_bounds__(256) void cast_bf16(const float* __restrict__ src,
                                                 us* __restrict__ dst, int n8) {
  const int i = blockIdx.x * 256 + threadIdx.x;
  if (i < n8) *(int4*)(dst + (size_t)i * 8) = stage8(src + (size_t)i * 8);
}

// ---------------------------------------------------------------------------
// 256x256 GEMM, BK=64, 2-barrier K-loop + counted vmcnt prefetch (R9-proven:
// 125 us QKV, MfmaUtil 34.6, conflicts 0). 512 threads = 8 waves (2M x 4N),
// per-wave 128x64 output. LDS: 2-deep double buffer, 128 KiB (1 block/CU).
// K-loop per tile t:
//   B0 barrier -> all waves finished reading tile t-1 (its buffer is free)
//   STAGE(t+1) -> 8 global_load_lds into buf[cur^1] (safe after B0)
//   vmcnt(8)   -> tile t's 8 loads landed; t+1's stay in flight
//   B1 barrier -> tile t visible to all waves
//   compute    -> 24 ds_read_b128 + 64 MFMA, NO barriers (waves drift)
// Swizzle: logical col-group g of row r stored at phys group g^(r&7);
// staging pre-swizzles the SOURCE col; fragment reads apply the same XOR.
// HM: head-major C store [mat][b*16+h][tok][d] for the QKV gemm.
// ---------------------------------------------------------------------------
template <int N, int K, int EPI, int HM, typename CT>
__global__ __launch_bounds__(512, 1) void gemm256(
    const us* __restrict__ A, const us* __restrict__ Bt,
    const float* __restrict__ bias, const float* __restrict__ resid,
    CT* __restrict__ C) {
  __shared__ __align__(16) us As[2][256 * 64];
  __shared__ __align__(16) us Bs[2][256 * 64];
  const int tid = threadIdx.x;
  const int lane = tid & 63;
  const int wave = tid >> 6;   // 0..7
  const int wm = wave >> 2;    // 0..1  (M half)
  const int wn = wave & 3;     // 0..3  (N quarter)
  const int lr = lane & 15, lq = lane >> 4;
  const int m0 = blockIdx.y * 256;
  const int n0 = blockIdx.x * 256;
  const int trow = tid >> 3;                        // 0..63 (row within 64-row pass)
  const int tcol = (((tid & 7) ^ (trow & 7)) * 8);  // XOR-swizzled src col

  constexpr int NT = K / 64;

  float4v acc[8][4];
#pragma unroll
  for (int i = 0; i < 8; i++)
#pragma unroll
    for (int j = 0; j < 4; j++) acc[i][j] = (float4v)0.0f;

#define STAGE256(buf, t)                                                       \
  do {                                                                         \
    const size_t kof = (size_t)(t) * 64;                                       \
    _Pragma("unroll") for (int q = 0; q < 4; q++) {                            \
      const us* ga = A + (size_t)(m0 + q * 64 + trow) * K + kof + tcol;        \
      __builtin_amdgcn_global_load_lds((GAS*)ga,                               \
          (LAS*)&As[buf][(q * 512 + tid) * 8], 16, 0, 0);                      \
    }                                                                          \
    _Pragma("unroll") for (int q = 0; q < 4; q++) {                            \
      const us* gb = Bt + (size_t)(n0 + q * 64 + trow) * K + kof + tcol;       \
      __builtin_amdgcn_global_load_lds((GAS*)gb,                               \
          (LAS*)&Bs[buf][(q * 512 + tid) * 8], 16, 0, 0);                      \
    }                                                                          \
  } while (0)

  STAGE256(0, 0);  // prologue: tile 0 in flight

  for (int t = 0; t < NT; t++) {
    const int cur = t & 1;
    __builtin_amdgcn_s_barrier();  // B0: tile t-1 reads complete everywhere
    if (t + 1 < NT) {
      STAGE256(cur ^ 1, t + 1);    // overwrite t-1's buffer (safe after B0)
      asm volatile("s_waitcnt vmcnt(8)" ::: "memory");  // tile t landed
    } else {
      asm volatile("s_waitcnt vmcnt(0)" ::: "memory");  // drain last tile
    }
    __builtin_amdgcn_s_barrier();  // B1: tile t visible to all waves

    const us* Ab = As[cur];
    const us* Bb = Bs[cur];
#pragma unroll
    for (int kk8 = 0; kk8 < 2; kk8++) {
      short8 bf8[4];
#pragma unroll
      for (int nt = 0; nt < 4; nt++) {
        const int row = wn * 64 + nt * 16 + lr;
        bf8[nt] = *(const short8*)&Bb[row * 64 + (((kk8 * 4 + lq) ^ (lr & 7)) * 8)];
      }
#pragma unroll
      for (int mh = 0; mh < 2; mh++) {
        short8 af[4];
#pragma unroll
        for (int mt = 0; mt < 4; mt++) {
          const int row = wm * 128 + mh * 64 + mt * 16 + lr;
          af[mt] = *(const short8*)&Ab[row * 64 + (((kk8 * 4 + lq) ^ (lr & 7)) * 8)];
        }
        __builtin_amdgcn_s_setprio(1);
#pragma unroll
        for (int mt = 0; mt < 4; mt++)
#pragma unroll
          for (int nt = 0; nt < 4; nt++)
            acc[mh * 4 + mt][nt] = __builtin_amdgcn_mfma_f32_16x16x32_bf16(
                af[mt], bf8[nt], acc[mh * 4 + mt][nt], 0, 0, 0);
        __builtin_amdgcn_s_setprio(0);
      }
    }
  }
#undef STAGE256

  float bb[4];
#pragma unroll
  for (int nt = 0; nt < 4; nt++) bb[nt] = bias[n0 + wn * 64 + nt * 16 + lr];
#pragma unroll
  for (int mh = 0; mh < 2; mh++)
#pragma unroll
    for (int mt = 0; mt < 4; mt++) {
      const int rbase = m0 + wm * 128 + mh * 64 + mt * 16 + lq * 4;
#pragma unroll
      for (int nt = 0; nt < 4; nt++) {
        const int col = n0 + wn * 64 + nt * 16 + lr;
#pragma unroll
        for (int r = 0; r < 4; r++) {
          float v = acc[mh * 4 + mt][nt][r] + bb[nt];
          const int row = rbase + r;
          size_t idx;
          if (HM) {
            // head-major: [mat][b*16+h][tok][d]
            const int mat = col >> 10, hh = (col >> 6) & 15, d = col & 63;
            idx = (size_t)mat * (16384u * 1024u) +
                  (size_t)((row >> 12) * 16 + hh) * (4096u * 64u) +
                  (size_t)(row & 4095) * 64 + d;
          } else {
            idx = (size_t)row * N + col;
          }
          if (EPI) v += resid[idx];
          stc(&C[idx], v);
        }
      }
    }
}

// ---------------------------------------------------------------------------
// MFMA windowed attention, head-major input, 1 window per block (R2-proven).
// Q/K/V for the window are contiguous 8 KB blocks -> L1-resident after
// first touch. Output stays [token][1024] for the proj gemm.
// ---------------------------------------------------------------------------
__global__ __launch_bounds__(256) void attn_mfma(
    const us* __restrict__ qkv, us* __restrict__ attn) {
  __shared__ __align__(16) us Vt[64 * 64];       // elem(d,j) at d*64+((j>>3)^(d&7))*8+(j&7)
  __shared__ __align__(16) us Pl[4 * 16 * 64];   // per-wave 16x64, same swizzle
  const int wid = blockIdx.x;
  const int wi = wid & 63;
  const int h = (wid >> 6) & 15;
  const int b = wid >> 10;
  const int tid = threadIdx.x;
  const int lane = tid & 63;
  const int w = tid >> 6;
  const int lr = lane & 15, lq = lane >> 4;
  const int rowbase = b * 4096 + wi * 64;

  // head-major window bases: contiguous 64x64 bf16 tiles
  const us* Qb = qkv + (size_t)(b * 16 + h) * (4096u * 64u) + (size_t)wi * 4096;
  const us* Kb = Qb + (size_t)16384 * 1024;
  const us* Vb = Kb + (size_t)16384 * 1024;

  // ---- stage V^T (swizzled): wave w covers d in [16w,16w+16) for all tokens
  {
    const int r = lane;  // token in window
    const int cs = w * 16;
    const us* vsrc = Vb + (size_t)r * 64 + cs;
    int4 v0 = *(const int4*)vsrc;
    int4 v1 = *(const int4*)(vsrc + 8);
    const us* vv0 = (const us*)&v0;
    const us* vv1 = (const us*)&v1;
#pragma unroll
    for (int i = 0; i < 8; i++) {
      const int d = cs + i;
      Vt[d * 64 + (((r >> 3) ^ (d & 7)) * 8) + (r & 7)] = vv0[i];
    }
#pragma unroll
    for (int i = 0; i < 8; i++) {
      const int d = cs + 8 + i;
      Vt[d * 64 + (((r >> 3) ^ (d & 7)) * 8) + (r & 7)] = vv1[i];
    }
  }

  // ---- S = Q K^T (rows 16w..16w+15), frags from global (L1-local)
  short8 aq[2];
  {
    const us* qrow = Qb + (size_t)(w * 16 + lr) * 64 + lq * 8;
    aq[0] = *(const short8*)qrow;
    aq[1] = *(const short8*)(qrow + 32);
  }
  float4v s[4];
#pragma unroll
  for (int nt = 0; nt < 4; nt++) s[nt] = (float4v)0.0f;
#pragma unroll
  for (int kk8 = 0; kk8 < 2; kk8++) {
#pragma unroll
    for (int nt = 0; nt < 4; nt++) {
      const us* krow = Kb + (size_t)(nt * 16 + lr) * 64 + kk8 * 32 + lq * 8;
      short8 bk = *(const short8*)krow;
      s[nt] = __builtin_amdgcn_mfma_f32_16x16x32_bf16(aq[kk8], bk, s[nt], 0, 0, 0);
    }
  }

  // ---- softmax per row
  float p[4][4];  // [nt][r]
#pragma unroll
  for (int r = 0; r < 4; r++) {
    float mx = -1e30f;
#pragma unroll
    for (int nt = 0; nt < 4; nt++) {
      s[nt][r] *= 0.125f;
      mx = fmaxf(mx, s[nt][r]);
    }
    mx = fmaxf(mx, __shfl_xor(mx, 1));
    mx = fmaxf(mx, __shfl_xor(mx, 2));
    mx = fmaxf(mx, __shfl_xor(mx, 4));
    mx = fmaxf(mx, __shfl_xor(mx, 8));
    float sum = 0.f;
#pragma unroll
    for (int nt = 0; nt < 4; nt++) {
      p[nt][r] = __expf(s[nt][r] - mx);
      sum += p[nt][r];
    }
    sum += __shfl_xor(sum, 1);
    sum += __shfl_xor(sum, 2);
    sum += __shfl_xor(sum, 4);
    sum += __shfl_xor(sum, 8);
    const float inv = 1.0f / sum;
#pragma unroll
    for (int nt = 0; nt < 4; nt++) p[nt][r] *= inv;
  }

  // ---- P -> LDS (per-wave region, swizzled), C-layout source
  us* pw = Pl + w * 1024;
#pragma unroll
  for (int nt = 0; nt < 4; nt++) {
    const int c = nt * 16 + lr;
#pragma unroll
    for (int r = 0; r < 4; r++) {
      const int row = lq * 4 + r;
      pw[row * 64 + (((c >> 3) ^ (row & 7)) * 8) + (c & 7)] = f2bf(p[nt][r]);
    }
  }
  __syncthreads();  // Vt (cross-wave) + P visible

  // ---- O = P V  (A-frag from Pl, B-frag from Vt)
  float4v o[4];
#pragma unroll
  for (int nt = 0; nt < 4; nt++) o[nt] = (float4v)0.0f;
#pragma unroll
  for (int kk8 = 0; kk8 < 2; kk8++) {
    short8 pa = *(const short8*)&pw[lr * 64 + (((lq + kk8 * 4) ^ (lr & 7)) * 8)];
#pragma unroll
    for (int nt = 0; nt < 4; nt++) {
      const int d = nt * 16 + lr;
      short8 vb = *(const short8*)&Vt[d * 64 + (((lq + kk8 * 4) ^ (d & 7)) * 8)];
      o[nt] = __builtin_amdgcn_mfma_f32_16x16x32_bf16(pa, vb, o[nt], 0, 0, 0);
    }
  }

  // ---- store O (C-layout): row = 16w+lq*4+r, col d = nt*16+lr
#pragma unroll
  for (int nt = 0; nt < 4; nt++) {
    const int d = nt * 16 + lr;
#pragma unroll
    for (int r = 0; r < 4; r++) {
      const int tok = rowbase + w * 16 + lq * 4 + r;
      attn[(size_t)tok * 1024 + h * 64 + d] = f2bf(o[nt][r]);
    }
  }
}

// ---------------------------------------------------------------------------
// FALLBACK GEMM (R5-proven, VGPR staging + convert, unswizzled)
// ---------------------------------------------------------------------------
template <int N, int K, int EPI, typename AT, typename CT>
__global__ __launch_bounds__(256) void gemm_bt(
    const AT* __restrict__ A, const float* __restrict__ Bt,
    const float* __restrict__ bias, const float* __restrict__ resid,
    CT* __restrict__ C) {
  __shared__ __align__(16) us As[128 * 64];
  __shared__ __align__(16) us Bs[128 * 64];
  const int tid = threadIdx.x;
  const int lane = tid & 63;
  const int wave = tid >> 6;
  const int wm = wave >> 1, wn = wave & 1;
  const int lr = lane & 15, lq = lane >> 4;
  const int m0 = blockIdx.y * 128;
  const int n0 = blockIdx.x * 128;
  const int trow = tid >> 3;
  const int tcol = (tid & 7) * 8;

  float4v acc[4][4];
#pragma unroll
  for (int i = 0; i < 4; i++)
#pragma unroll
    for (int j = 0; j < 4; j++) acc[i][j] = (float4v)0.0f;

  for (int k0 = 0; k0 < K; k0 += 64) {
    int4 av[4], bv[4];
#pragma unroll
    for (int p = 0; p < 4; p++) {
      av[p] = stage8(A + (size_t)(m0 + p * 32 + trow) * K + k0 + tcol);
      bv[p] = stage8(Bt + (size_t)(n0 + p * 32 + trow) * K + k0 + tcol);
    }
#pragma unroll
    for (int p = 0; p < 4; p++) {
      *(int4*)&As[(p * 256 + tid) * 8] = av[p];
      *(int4*)&Bs[(p * 256 + tid) * 8] = bv[p];
    }
    __syncthreads();
#pragma unroll
    for (int kk = 0; kk < 64; kk += 32) {
      short8 af[4], bfv[4];
#pragma unroll
      for (int mt = 0; mt < 4; mt++)
        af[mt] = *(const short8*)&As[(wm * 64 + mt * 16 + lr) * 64 + kk + lq * 8];
#pragma unroll
      for (int nt = 0; nt < 4; nt++)
        bfv[nt] = *(const short8*)&Bs[(wn * 64 + nt * 16 + lr) * 64 + kk + lq * 8];
#pragma unroll
      for (int mt = 0; mt < 4; mt++)
#pragma unroll
        for (int nt = 0; nt < 4; nt++)
          acc[mt][nt] = __builtin_amdgcn_mfma_f32_16x16x32_bf16(
              af[mt], bfv[nt], acc[mt][nt], 0, 0, 0);
    }
    __syncthreads();
  }

  float bb[4];
#pragma unroll
  for (int nt = 0; nt < 4; nt++) bb[nt] = bias[n0 + wn * 64 + nt * 16 + lr];
#pragma unroll
  for (int mt = 0; mt < 4; mt++) {
    const int rbase = m0 + wm * 64 + mt * 16 + lq * 4;
#pragma unroll
    for (int nt = 0; nt < 4; nt++) {
      const int col = n0 + wn * 64 + nt * 16 + lr;
#pragma unroll
      for (int r = 0; r < 4; r++) {
        float v = acc[mt][nt][r] + bb[nt];
        size_t idx = (size_t)(rbase + r) * N + col;
        if (EPI) v += resid[idx];
        stc(&C[idx], v);
      }
    }
  }
}

// ---------------------------------------------------------------------------
// Fallback VALU attention (R5-proven, row-major qkv)
// ---------------------------------------------------------------------------
__global__ __launch_bounds__(256) void attn_win(
    const us* __restrict__ qkv, us* __restrict__ attn) {
  __shared__ float qs[64][65];
  __shared__ float ks[64][65];
  __shared__ float vs[64][65];
  const int wid = blockIdx.x;
  const int wi = wid & 63;
  const int h = (wid >> 6) & 15;
  const int b = wid >> 10;
  const int t = threadIdx.x;
  const int rowbase = b * 4096 + wi * 64;
  {
    const int r = t >> 2;
    const int cs = (t & 3) * 16;
    const us* base = qkv + (size_t)(rowbase + r) * 3072 + h * 64 + cs;
#pragma unroll
    for (int s = 0; s < 3; s++) {
      float* dst = (s == 0) ? &qs[r][cs] : (s == 1) ? &ks[r][cs] : &vs[r][cs];
      const us* src = base + s * 1024;
#pragma unroll
      for (int half = 0; half < 2; half++) {
        int4 dv = *(const int4*)(src + half * 8);
        const us* tp = (const us*)&dv;
#pragma unroll
        for (int i = 0; i < 8; i++) dst[half * 8 + i] = bf2f(tp[i]);
      }
    }
  }
  __syncthreads();
  const int r0 = (t >> 4) * 4;
  const int c0 = (t & 15) * 4;
  float acc[4][4] = {};
#pragma unroll 8
  for (int k = 0; k < 64; k++) {
    float qv[4], kv[4];
#pragma unroll
    for (int i = 0; i < 4; i++) qv[i] = qs[r0 + i][k];
#pragma unroll
    for (int j = 0; j < 4; j++) kv[j] = ks[c0 + j][k];
#pragma unroll
    for (int i = 0; i < 4; i++)
#pragma unroll
      for (int j = 0; j < 4; j++) acc[i][j] += qv[i] * kv[j];
  }
  __syncthreads();
#pragma unroll
  for (int i = 0; i < 4; i++)
#pragma unroll
    for (int j = 0; j < 4; j++) qs[r0 + i][c0 + j] = acc[i][j] * 0.125f;
  __syncthreads();
  {
    const int rr = t >> 2;
    const int cs = (t & 3) * 16;
    float pv[16];
    float m = -1e30f;
#pragma unroll
    for (int i = 0; i < 16; i++) {
      pv[i] = qs[rr][cs + i];
      m = fmaxf(m, pv[i]);
    }
    m = fmaxf(m, __shfl_xor(m, 1));
    m = fmaxf(m, __shfl_xor(m, 2));
    float ssum = 0.f;
#pragma unroll
    for (int i = 0; i < 16; i++) {
      pv[i] = __expf(pv[i] - m);
      ssum += pv[i];
    }
    ssum += __shfl_xor(ssum, 1);
    ssum += __shfl_xor(ssum, 2);
    const float inv = 1.0f / ssum;
#pragma unroll
    for (int i = 0; i < 16; i++) qs[rr][cs + i] = pv[i] * inv;
  }
  __syncthreads();
  float o[4][4] = {};
#pragma unroll 8
  for (int k = 0; k < 64; k++) {
    float pr[4], vv[4];
#pragma unroll
    for (int i = 0; i < 4; i++) pr[i] = qs[r0 + i][k];
#pragma unroll
    for (int j = 0; j < 4; j++) vv[j] = vs[k][c0 + j];
#pragma unroll
    for (int i = 0; i < 4; i++)
#pragma unroll
      for (int j = 0; j < 4; j++) o[i][j] += pr[i] * vv[j];
  }
#pragma unroll
  for (int i = 0; i < 4; i++)
#pragma unroll
    for (int j = 0; j < 4; j++)
      attn[(size_t)(rowbase + r0 + i) * 1024 + h * 64 + c0 + j] = f2bf(o[i][j]);
}

// ---------------------------------------------------------------------------
// In-place fp32 LayerNorm, one WAVE per row: no LDS, no barriers.
// 4 rows per 256-thread block (grid 4096). Lane l of wave w covers cols
// (i*64+l)*4..+3 for i=0..3; wave-wide shuffle reduce (6 steps).
// ---------------------------------------------------------------------------
__global__ __launch_bounds__(256) void ln_wave(
    float* __restrict__ y, const float* __restrict__ gamma,
    const float* __restrict__ beta) {
  const int row = blockIdx.x * 4 + (threadIdx.x >> 6);
  const int lane = threadIdx.x & 63;
  float* yr = y + (size_t)row * 1024;
  float4 v[4];
  float s1 = 0.f, s2 = 0.f;
#pragma unroll
  for (int i = 0; i < 4; i++) {
    v[i] = *(const float4*)(yr + (i * 64 + lane) * 4);
    s1 += v[i].x + v[i].y + v[i].z + v[i].w;
    s2 += v[i].x * v[i].x + v[i].y * v[i].y + v[i].z * v[i].z + v[i].w * v[i].w;
  }
#pragma unroll
  for (int off = 32; off > 0; off >>= 1) {
    s1 += __shfl_xor(s1, off);
    s2 += __shfl_xor(s2, off);
  }
  const float mean = s1 * (1.0f / 1024.0f);
  const float var = s2 * (1.0f / 1024.0f) - mean * mean;
  const float rstd = rsqrtf(var + 1e-5f);
#pragma unroll
  for (int i = 0; i < 4; i++) {
    float4 g = *(const float4*)(gamma + (i * 64 + lane) * 4);
    float4 bt = *(const float4*)(beta + (i * 64 + lane) * 4);
    float4 o;
    o.x = (v[i].x - mean) * rstd * g.x + bt.x;
    o.y = (v[i].y - mean) * rstd * g.y + bt.y;
    o.z = (v[i].z - mean) * rstd * g.z + bt.z;
    o.w = (v[i].w - mean) * rstd * g.w + bt.w;
    *(float4*)(yr + (i * 64 + lane) * 4) = o;
  }
}

// ---------------------------------------------------------------------------
extern "C" void kernel_launch(void* const* d_in, const int* in_sizes, int n_in,
                              void* d_out, int out_size, void* d_ws,
                              size_t ws_size, hipStream_t stream) {
  const float* x = (const float*)d_in[0];
  const float* Wqkv = (const float*)d_in[1];
  const float* bqkv = (const float*)d_in[2];
  const float* Wproj = (const float*)d_in[3];
  const float* bproj = (const float*)d_in[4];
  const float* gamma = (const float*)d_in[5];
  const float* beta = (const float*)d_in[6];
  float* out = (float*)d_out;

  us* qkv = (us*)d_ws;                        // 16384*3072 (100.7 MB)
  us* attn = qkv + (size_t)16384 * 3072;      // 16384*1024 (33.6 MB)
  us* xb = attn + (size_t)16384 * 1024;       // 16384*1024 (33.6 MB)
  us* Wqkvb = xb + (size_t)16384 * 1024;      // 3072*1024  (6.3 MB)
  us* Wprojb = Wqkvb + (size_t)3072 * 1024;   // 1024*1024  (2.1 MB)
  const size_t need =
      ((size_t)16384 * 3072 + 3 * (size_t)16384 * 1024 + (size_t)3072 * 1024 +
       (size_t)1024 * 1024) * sizeof(us);

  if (ws_size >= need) {
    cast_bf16<<<(16384 * 1024 / 8 + 255) / 256, 256, 0, stream>>>(x, xb,
                                                                  16384 * 128);
    cast_bf16<<<(3072 * 1024 / 8 + 255) / 256, 256, 0, stream>>>(Wqkv, Wqkvb,
                                                                 3072 * 128);
    cast_bf16<<<(1024 * 1024 / 8 + 255) / 256, 256, 0, stream>>>(Wproj, Wprojb,
                                                                 1024 * 128);
    gemm256<3072, 1024, 0, 1, us><<<dim3(12, 64), 512, 0, stream>>>(
        xb, Wqkvb, bqkv, nullptr, qkv);
    attn_mfma<<<4096, 256, 0, stream>>>(qkv, attn);
    gemm256<1024, 1024, 1, 0, float><<<dim3(4, 64), 512, 0, stream>>>(
        attn, Wprojb, bproj, x, out);
  } else {
    gemm_bt<3072, 1024, 0, float, us><<<dim3(24, 128), 256, 0, stream>>>(
        x, Wqkv, bqkv, nullptr, qkv);
    attn_win<<<4096, 256, 0, stream>>>(qkv, attn);
    gemm_bt<1024, 1024, 1, us, float><<<dim3(8, 128), 256, 0, stream>>>(
        attn, Wproj, bproj, x, out);
  }
  ln_wave<<<4096, 256, 0, stream>>>(out, gamma, beta);
}

// Round 8
// 345.147 us; speedup vs baseline: 1.2347x; 1.0284x over previous
//
#include <hip/hip_runtime.h>
#include <stdint.h>

// LocalAttention: y = LN(x + proj(attn(qkv(x)))). fp32 inputs, fp32 output.
// B=4 L=4096 D=1024 H=16 W=HD=64 -> M=16384 rows.
//
// R15 (on top of the reproduced 355 us R14 composition):
//  (a) attn O-store coalescing: O round-trips through the per-wave Pl LDS
//      region (wave-private -> no new barrier; same-wave lgkmcnt ordering),
//      then 2x16B stores per lane forming full 128B row segments. Replaces
//      16 scattered 2B global stores/thread (4x32B partial sectors/wave).
//      Write uses the proven P-swizzle (2-way banks); readback uses the
//      g^(row&7) group pattern (conflict-free, same as GEMM frag reads).
//  (b) XCD-bijective block swizzle on gemm256 (768/256 blocks, %8==0):
//      chunked remap gives each XCD contiguous m-rows -> A panel fetched by
//      one XCD. Attribution via FETCH_SIZE (151.6 MB -> expect 60-90 MB).

typedef __attribute__((ext_vector_type(8))) short short8;
typedef __attribute__((ext_vector_type(4))) float float4v;
typedef unsigned short us;

#define GAS const __attribute__((address_space(1))) void
#define LAS __attribute__((address_space(3))) void

__device__ __forceinline__ float bf2f(us u) {
  return __uint_as_float(((unsigned int)u) << 16);
}
__device__ __forceinline__ us f2bf(float f) {
  unsigned int u = __float_as_uint(f);
  unsigned int r = u + 0x7FFFu + ((u >> 16) & 1u);
  return (us)(r >> 16);
}
__device__ __forceinline__ int4 stage8(const float* p) {
  float4 a = *(const float4*)p;
  float4 b = *(const float4*)(p + 4);
  int4 r;
  us* u = (us*)&r;
  u[0] = f2bf(a.x); u[1] = f2bf(a.y); u[2] = f2bf(a.z); u[3] = f2bf(a.w);
  u[4] = f2bf(b.x); u[5] = f2bf(b.y); u[6] = f2bf(b.z); u[7] = f2bf(b.w);
  return r;
}
__device__ __forceinline__ int4 stage8(const us* p) { return *(const int4*)p; }
__device__ __forceinline__ void stc(us* p, float v) { *p = f2bf(v); }
__device__ __forceinline__ void stc(float* p, float v) { *p = v; }

// ---------------------------------------------------------------------------
// fp32 -> bf16 precast, 8 elems/thread
// ---------------------------------------------------------------------------
__global__ __launch_bounds__(256) void cast_bf16(const float* __restrict__ src,
                                                 us* __restrict__ dst, int n8) {
  const int i = blockIdx.x * 256 + threadIdx.x;
  if (i < n8) *(int4*)(dst + (size_t)i * 8) = stage8(src + (size_t)i * 8);
}

// ---------------------------------------------------------------------------
// 256x256 GEMM, BK=64, 2-barrier K-loop + counted vmcnt prefetch (R9-proven:
// MfmaUtil ~34.6, conflicts 0). 512 threads = 8 waves (2M x 4N), per-wave
// 128x64 output. LDS: 2-deep double buffer, 128 KiB (1 block/CU).
// K-loop per tile t:
//   B0 barrier -> all waves finished reading tile t-1 (its buffer is free)
//   STAGE(t+1) -> 8 global_load_lds into buf[cur^1] (safe after B0)
//   vmcnt(8)   -> tile t's 8 loads landed; t+1's stay in flight
//   B1 barrier -> tile t visible to all waves
//   compute    -> 24 ds_read_b128 + 64 MFMA, NO barriers (waves drift)
// Swizzle: logical col-group g of row r stored at phys group g^(r&7);
// staging pre-swizzles the SOURCE col; fragment reads apply the same XOR.
// XCD: chunked bijective remap (NWG%8==0) -> each XCD owns contiguous
// m-rows so each A panel is fetched by exactly one XCD.
// HM: head-major C store [mat][b*16+h][tok][d] for the QKV gemm.
// ---------------------------------------------------------------------------
template <int N, int K, int EPI, int HM, typename CT>
__global__ __launch_bounds__(512, 1) void gemm256(
    const us* __restrict__ A, const us* __restrict__ Bt,
    const float* __restrict__ bias, const float* __restrict__ resid,
    CT* __restrict__ C) {
  constexpr int NBX = N / 256;
  constexpr int NWG = NBX * 64;  // 16384/256 m-tiles
  __shared__ __align__(16) us As[2][256 * 64];
  __shared__ __align__(16) us Bs[2][256 * 64];
  const int tid = threadIdx.x;
  const int lane = tid & 63;
  const int wave = tid >> 6;   // 0..7
  const int wm = wave >> 2;    // 0..1  (M half)
  const int wn = wave & 3;     // 0..3  (N quarter)
  const int lr = lane & 15, lq = lane >> 4;

  int id = blockIdx.y * NBX + blockIdx.x;
  id = (id & 7) * (NWG / 8) + (id >> 3);  // XCD-contiguous tile ranges
  const int m0 = (id / NBX) * 256;
  const int n0 = (id % NBX) * 256;

  const int trow = tid >> 3;                        // 0..63 (row within 64-row pass)
  const int tcol = (((tid & 7) ^ (trow & 7)) * 8);  // XOR-swizzled src col

  constexpr int NT = K / 64;

  float4v acc[8][4];
#pragma unroll
  for (int i = 0; i < 8; i++)
#pragma unroll
    for (int j = 0; j < 4; j++) acc[i][j] = (float4v)0.0f;

#define STAGE256(buf, t)                                                       \
  do {                                                                         \
    const size_t kof = (size_t)(t) * 64;                                       \
    _Pragma("unroll") for (int q = 0; q < 4; q++) {                            \
      const us* ga = A + (size_t)(m0 + q * 64 + trow) * K + kof + tcol;        \
      __builtin_amdgcn_global_load_lds((GAS*)ga,                               \
          (LAS*)&As[buf][(q * 512 + tid) * 8], 16, 0, 0);                      \
    }                                                                          \
    _Pragma("unroll") for (int q = 0; q < 4; q++) {                            \
      const us* gb = Bt + (size_t)(n0 + q * 64 + trow) * K + kof + tcol;       \
      __builtin_amdgcn_global_load_lds((GAS*)gb,                               \
          (LAS*)&Bs[buf][(q * 512 + tid) * 8], 16, 0, 0);                      \
    }                                                                          \
  } while (0)

  STAGE256(0, 0);  // prologue: tile 0 in flight

  for (int t = 0; t < NT; t++) {
    const int cur = t & 1;
    __builtin_amdgcn_s_barrier();  // B0: tile t-1 reads complete everywhere
    if (t + 1 < NT) {
      STAGE256(cur ^ 1, t + 1);    // overwrite t-1's buffer (safe after B0)
      asm volatile("s_waitcnt vmcnt(8)" ::: "memory");  // tile t landed
    } else {
      asm volatile("s_waitcnt vmcnt(0)" ::: "memory");  // drain last tile
    }
    __builtin_amdgcn_s_barrier();  // B1: tile t visible to all waves

    const us* Ab = As[cur];
    const us* Bb = Bs[cur];
#pragma unroll
    for (int kk8 = 0; kk8 < 2; kk8++) {
      short8 bf8[4];
#pragma unroll
      for (int nt = 0; nt < 4; nt++) {
        const int row = wn * 64 + nt * 16 + lr;
        bf8[nt] = *(const short8*)&Bb[row * 64 + (((kk8 * 4 + lq) ^ (lr & 7)) * 8)];
      }
#pragma unroll
      for (int mh = 0; mh < 2; mh++) {
        short8 af[4];
#pragma unroll
        for (int mt = 0; mt < 4; mt++) {
          const int row = wm * 128 + mh * 64 + mt * 16 + lr;
          af[mt] = *(const short8*)&Ab[row * 64 + (((kk8 * 4 + lq) ^ (lr & 7)) * 8)];
        }
        __builtin_amdgcn_s_setprio(1);
#pragma unroll
        for (int mt = 0; mt < 4; mt++)
#pragma unroll
          for (int nt = 0; nt < 4; nt++)
            acc[mh * 4 + mt][nt] = __builtin_amdgcn_mfma_f32_16x16x32_bf16(
                af[mt], bf8[nt], acc[mh * 4 + mt][nt], 0, 0, 0);
        __builtin_amdgcn_s_setprio(0);
      }
    }
  }
#undef STAGE256

  float bb[4];
#pragma unroll
  for (int nt = 0; nt < 4; nt++) bb[nt] = bias[n0 + wn * 64 + nt * 16 + lr];
#pragma unroll
  for (int mh = 0; mh < 2; mh++)
#pragma unroll
    for (int mt = 0; mt < 4; mt++) {
      const int rbase = m0 + wm * 128 + mh * 64 + mt * 16 + lq * 4;
#pragma unroll
      for (int nt = 0; nt < 4; nt++) {
        const int col = n0 + wn * 64 + nt * 16 + lr;
#pragma unroll
        for (int r = 0; r < 4; r++) {
          float v = acc[mh * 4 + mt][nt][r] + bb[nt];
          const int row = rbase + r;
          size_t idx;
          if (HM) {
            // head-major: [mat][b*16+h][tok][d]
            const int mat = col >> 10, hh = (col >> 6) & 15, d = col & 63;
            idx = (size_t)mat * (16384u * 1024u) +
                  (size_t)((row >> 12) * 16 + hh) * (4096u * 64u) +
                  (size_t)(row & 4095) * 64 + d;
          } else {
            idx = (size_t)row * N + col;
          }
          if (EPI) v += resid[idx];
          stc(&C[idx], v);
        }
      }
    }
}

// ---------------------------------------------------------------------------
// MFMA windowed attention, head-major input, 1 window per block (R2-proven),
// + R15 coalesced O store (O -> per-wave LDS -> 2x16B stores per lane,
// full 128B row segments; no new barrier).
// ---------------------------------------------------------------------------
__global__ __launch_bounds__(256) void attn_mfma(
    const us* __restrict__ qkv, us* __restrict__ attn) {
  __shared__ __align__(16) us Vt[64 * 64];       // elem(d,j) at d*64+((j>>3)^(d&7))*8+(j&7)
  __shared__ __align__(16) us Pl[4 * 16 * 64];   // per-wave 16x64, swizzled
  const int wid = blockIdx.x;
  const int wi = wid & 63;
  const int h = (wid >> 6) & 15;
  const int b = wid >> 10;
  const int tid = threadIdx.x;
  const int lane = tid & 63;
  const int w = tid >> 6;
  const int lr = lane & 15, lq = lane >> 4;
  const int rowbase = b * 4096 + wi * 64;

  // head-major window bases: contiguous 64x64 bf16 tiles
  const us* Qb = qkv + (size_t)(b * 16 + h) * (4096u * 64u) + (size_t)wi * 4096;
  const us* Kb = Qb + (size_t)16384 * 1024;
  const us* Vb = Kb + (size_t)16384 * 1024;

  // ---- stage V^T (swizzled): wave w covers d in [16w,16w+16) for all tokens
  {
    const int r = lane;  // token in window
    const int cs = w * 16;
    const us* vsrc = Vb + (size_t)r * 64 + cs;
    int4 v0 = *(const int4*)vsrc;
    int4 v1 = *(const int4*)(vsrc + 8);
    const us* vv0 = (const us*)&v0;
    const us* vv1 = (const us*)&v1;
#pragma unroll
    for (int i = 0; i < 8; i++) {
      const int d = cs + i;
      Vt[d * 64 + (((r >> 3) ^ (d & 7)) * 8) + (r & 7)] = vv0[i];
    }
#pragma unroll
    for (int i = 0; i < 8; i++) {
      const int d = cs + 8 + i;
      Vt[d * 64 + (((r >> 3) ^ (d & 7)) * 8) + (r & 7)] = vv1[i];
    }
  }

  // ---- S = Q K^T (rows 16w..16w+15), frags from global (L1-local)
  short8 aq[2];
  {
    const us* qrow = Qb + (size_t)(w * 16 + lr) * 64 + lq * 8;
    aq[0] = *(const short8*)qrow;
    aq[1] = *(const short8*)(qrow + 32);
  }
  float4v s[4];
#pragma unroll
  for (int nt = 0; nt < 4; nt++) s[nt] = (float4v)0.0f;
#pragma unroll
  for (int kk8 = 0; kk8 < 2; kk8++) {
#pragma unroll
    for (int nt = 0; nt < 4; nt++) {
      const us* krow = Kb + (size_t)(nt * 16 + lr) * 64 + kk8 * 32 + lq * 8;
      short8 bk = *(const short8*)krow;
      s[nt] = __builtin_amdgcn_mfma_f32_16x16x32_bf16(aq[kk8], bk, s[nt], 0, 0, 0);
    }
  }

  // ---- softmax per row (row = lq*4+r within the wave's 16-row strip)
  float p[4][4];  // [nt][r]
#pragma unroll
  for (int r = 0; r < 4; r++) {
    float mx = -1e30f;
#pragma unroll
    for (int nt = 0; nt < 4; nt++) {
      s[nt][r] *= 0.125f;
      mx = fmaxf(mx, s[nt][r]);
    }
    mx = fmaxf(mx, __shfl_xor(mx, 1));
    mx = fmaxf(mx, __shfl_xor(mx, 2));
    mx = fmaxf(mx, __shfl_xor(mx, 4));
    mx = fmaxf(mx, __shfl_xor(mx, 8));
    float sum = 0.f;
#pragma unroll
    for (int nt = 0; nt < 4; nt++) {
      p[nt][r] = __expf(s[nt][r] - mx);
      sum += p[nt][r];
    }
    sum += __shfl_xor(sum, 1);
    sum += __shfl_xor(sum, 2);
    sum += __shfl_xor(sum, 4);
    sum += __shfl_xor(sum, 8);
    const float inv = 1.0f / sum;
#pragma unroll
    for (int nt = 0; nt < 4; nt++) p[nt][r] *= inv;
  }

  // ---- P -> LDS (per-wave region, swizzled), C-layout source
  us* pw = Pl + w * 1024;
#pragma unroll
  for (int nt = 0; nt < 4; nt++) {
    const int c = nt * 16 + lr;
#pragma unroll
    for (int r = 0; r < 4; r++) {
      const int row = lq * 4 + r;
      pw[row * 64 + (((c >> 3) ^ (row & 7)) * 8) + (c & 7)] = f2bf(p[nt][r]);
    }
  }
  __syncthreads();  // Vt (cross-wave) + P visible

  // ---- O = P V  (A-frag from Pl, B-frag from Vt)
  float4v o[4];
#pragma unroll
  for (int nt = 0; nt < 4; nt++) o[nt] = (float4v)0.0f;
#pragma unroll
  for (int kk8 = 0; kk8 < 2; kk8++) {
    short8 pa = *(const short8*)&pw[lr * 64 + (((lq + kk8 * 4) ^ (lr & 7)) * 8)];
#pragma unroll
    for (int nt = 0; nt < 4; nt++) {
      const int d = nt * 16 + lr;
      short8 vb = *(const short8*)&Vt[d * 64 + (((lq + kk8 * 4) ^ (d & 7)) * 8)];
      o[nt] = __builtin_amdgcn_mfma_f32_16x16x32_bf16(pa, vb, o[nt], 0, 0, 0);
    }
  }

  // ---- O -> per-wave LDS (reuse pw; PV's pw reads are same-wave, ordered
  // by lgkmcnt -> no barrier), then coalesced 2x16B stores per lane.
#pragma unroll
  for (int nt = 0; nt < 4; nt++) {
    const int c = nt * 16 + lr;
#pragma unroll
    for (int r = 0; r < 4; r++) {
      const int row = lq * 4 + r;
      pw[row * 64 + (((c >> 3) ^ (row & 7)) * 8) + (c & 7)] = f2bf(o[nt][r]);
    }
  }
  {
    // lane l: row = l&15, d-segment lq*16..lq*16+15 (two swizzled 8-groups)
    const int row = lr;
    const int g0 = ((lq * 2) ^ (row & 7)) * 8;
    const int g1 = ((lq * 2 + 1) ^ (row & 7)) * 8;
    int4 v0 = *(const int4*)&pw[row * 64 + g0];
    int4 v1 = *(const int4*)&pw[row * 64 + g1];
    us* dst = attn + (size_t)(rowbase + w * 16 + row) * 1024 + h * 64 + lq * 16;
    *(int4*)dst = v0;
    *(int4*)(dst + 8) = v1;
  }
}

// ---------------------------------------------------------------------------
// FALLBACK GEMM (R5-proven, VGPR staging + convert, unswizzled)
// ---------------------------------------------------------------------------
template <int N, int K, int EPI, typename AT, typename CT>
__global__ __launch_bounds__(256) void gemm_bt(
    const AT* __restrict__ A, const float* __restrict__ Bt,
    const float* __restrict__ bias, const float* __restrict__ resid,
    CT* __restrict__ C) {
  __shared__ __align__(16) us As[128 * 64];
  __shared__ __align__(16) us Bs[128 * 64];
  const int tid = threadIdx.x;
  const int lane = tid & 63;
  const int wave = tid >> 6;
  const int wm = wave >> 1, wn = wave & 1;
  const int lr = lane & 15, lq = lane >> 4;
  const int m0 = blockIdx.y * 128;
  const int n0 = blockIdx.x * 128;
  const int trow = tid >> 3;
  const int tcol = (tid & 7) * 8;

  float4v acc[4][4];
#pragma unroll
  for (int i = 0; i < 4; i++)
#pragma unroll
    for (int j = 0; j < 4; j++) acc[i][j] = (float4v)0.0f;

  for (int k0 = 0; k0 < K; k0 += 64) {
    int4 av[4], bv[4];
#pragma unroll
    for (int p = 0; p < 4; p++) {
      av[p] = stage8(A + (size_t)(m0 + p * 32 + trow) * K + k0 + tcol);
      bv[p] = stage8(Bt + (size_t)(n0 + p * 32 + trow) * K + k0 + tcol);
    }
#pragma unroll
    for (int p = 0; p < 4; p++) {
      *(int4*)&As[(p * 256 + tid) * 8] = av[p];
      *(int4*)&Bs[(p * 256 + tid) * 8] = bv[p];
    }
    __syncthreads();
#pragma unroll
    for (int kk = 0; kk < 64; kk += 32) {
      short8 af[4], bfv[4];
#pragma unroll
      for (int mt = 0; mt < 4; mt++)
        af[mt] = *(const short8*)&As[(wm * 64 + mt * 16 + lr) * 64 + kk + lq * 8];
#pragma unroll
      for (int nt = 0; nt < 4; nt++)
        bfv[nt] = *(const short8*)&Bs[(wn * 64 + nt * 16 + lr) * 64 + kk + lq * 8];
#pragma unroll
      for (int mt = 0; mt < 4; mt++)
#pragma unroll
        for (int nt = 0; nt < 4; nt++)
          acc[mt][nt] = __builtin_amdgcn_mfma_f32_16x16x32_bf16(
              af[mt], bfv[nt], acc[mt][nt], 0, 0, 0);
    }
    __syncthreads();
  }

  float bb[4];
#pragma unroll
  for (int nt = 0; nt < 4; nt++) bb[nt] = bias[n0 + wn * 64 + nt * 16 + lr];
#pragma unroll
  for (int mt = 0; mt < 4; mt++) {
    const int rbase = m0 + wm * 64 + mt * 16 + lq * 4;
#pragma unroll
    for (int nt = 0; nt < 4; nt++) {
      const int col = n0 + wn * 64 + nt * 16 + lr;
#pragma unroll
      for (int r = 0; r < 4; r++) {
        float v = acc[mt][nt][r] + bb[nt];
        size_t idx = (size_t)(rbase + r) * N + col;
        if (EPI) v += resid[idx];
        stc(&C[idx], v);
      }
    }
  }
}

// ---------------------------------------------------------------------------
// Fallback VALU attention (R5-proven, row-major qkv)
// ---------------------------------------------------------------------------
__global__ __launch_bounds__(256) void attn_win(
    const us* __restrict__ qkv, us* __restrict__ attn) {
  __shared__ float qs[64][65];
  __shared__ float ks[64][65];
  __shared__ float vs[64][65];
  const int wid = blockIdx.x;
  const int wi = wid & 63;
  const int h = (wid >> 6) & 15;
  const int b = wid >> 10;
  const int t = threadIdx.x;
  const int rowbase = b * 4096 + wi * 64;
  {
    const int r = t >> 2;
    const int cs = (t & 3) * 16;
    const us* base = qkv + (size_t)(rowbase + r) * 3072 + h * 64 + cs;
#pragma unroll
    for (int s = 0; s < 3; s++) {
      float* dst = (s == 0) ? &qs[r][cs] : (s == 1) ? &ks[r][cs] : &vs[r][cs];
      const us* src = base + s * 1024;
#pragma unroll
      for (int half = 0; half < 2; half++) {
        int4 dv = *(const int4*)(src + half * 8);
        const us* tp = (const us*)&dv;
#pragma unroll
        for (int i = 0; i < 8; i++) dst[half * 8 + i] = bf2f(tp[i]);
      }
    }
  }
  __syncthreads();
  const int r0 = (t >> 4) * 4;
  const int c0 = (t & 15) * 4;
  float acc[4][4] = {};
#pragma unroll 8
  for (int k = 0; k < 64; k++) {
    float qv[4], kv[4];
#pragma unroll
    for (int i = 0; i < 4; i++) qv[i] = qs[r0 + i][k];
#pragma unroll
    for (int j = 0; j < 4; j++) kv[j] = ks[c0 + j][k];
#pragma unroll
    for (int i = 0; i < 4; i++)
#pragma unroll
      for (int j = 0; j < 4; j++) acc[i][j] += qv[i] * kv[j];
  }
  __syncthreads();
#pragma unroll
  for (int i = 0; i < 4; i++)
#pragma unroll
    for (int j = 0; j < 4; j++) qs[r0 + i][c0 + j] = acc[i][j] * 0.125f;
  __syncthreads();
  {
    const int rr = t >> 2;
    const int cs = (t & 3) * 16;
    float pv[16];
    float m = -1e30f;
#pragma unroll
    for (int i = 0; i < 16; i++) {
      pv[i] = qs[rr][cs + i];
      m = fmaxf(m, pv[i]);
    }
    m = fmaxf(m, __shfl_xor(m, 1));
    m = fmaxf(m, __shfl_xor(m, 2));
    float ssum = 0.f;
#pragma unroll
    for (int i = 0; i < 16; i++) {
      pv[i] = __expf(pv[i] - m);
      ssum += pv[i];
    }
    ssum += __shfl_xor(ssum, 1);
    ssum += __shfl_xor(ssum, 2);
    const float inv = 1.0f / ssum;
#pragma unroll
    for (int i = 0; i < 16; i++) qs[rr][cs + i] = pv[i] * inv;
  }
  __syncthreads();
  float o[4][4] = {};
#pragma unroll 8
  for (int k = 0; k < 64; k++) {
    float pr[4], vv[4];
#pragma unroll
    for (int i = 0; i < 4; i++) pr[i] = qs[r0 + i][k];
#pragma unroll
    for (int j = 0; j < 4; j++) vv[j] = vs[k][c0 + j];
#pragma unroll
    for (int i = 0; i < 4; i++)
#pragma unroll
      for (int j = 0; j < 4; j++) o[i][j] += pr[i] * vv[j];
  }
#pragma unroll
  for (int i = 0; i < 4; i++)
#pragma unroll
    for (int j = 0; j < 4; j++)
      attn[(size_t)(rowbase + r0 + i) * 1024 + h * 64 + c0 + j] = f2bf(o[i][j]);
}

// ---------------------------------------------------------------------------
// In-place fp32 LayerNorm, one WAVE per row: no LDS, no barriers.
// ---------------------------------------------------------------------------
__global__ __launch_bounds__(256) void ln_wave(
    float* __restrict__ y, const float* __restrict__ gamma,
    const float* __restrict__ beta) {
  const int row = blockIdx.x * 4 + (threadIdx.x >> 6);
  const int lane = threadIdx.x & 63;
  float* yr = y + (size_t)row * 1024;
  float4 v[4];
  float s1 = 0.f, s2 = 0.f;
#pragma unroll
  for (int i = 0; i < 4; i++) {
    v[i] = *(const float4*)(yr + (i * 64 + lane) * 4);
    s1 += v[i].x + v[i].y + v[i].z + v[i].w;
    s2 += v[i].x * v[i].x + v[i].y * v[i].y + v[i].z * v[i].z + v[i].w * v[i].w;
  }
#pragma unroll
  for (int off = 32; off > 0; off >>= 1) {
    s1 += __shfl_xor(s1, off);
    s2 += __shfl_xor(s2, off);
  }
  const float mean = s1 * (1.0f / 1024.0f);
  const float var = s2 * (1.0f / 1024.0f) - mean * mean;
  const float rstd = rsqrtf(var + 1e-5f);
#pragma unroll
  for (int i = 0; i < 4; i++) {
    float4 g = *(const float4*)(gamma + (i * 64 + lane) * 4);
    float4 bt = *(const float4*)(beta + (i * 64 + lane) * 4);
    float4 o;
    o.x = (v[i].x - mean) * rstd * g.x + bt.x;
    o.y = (v[i].y - mean) * rstd * g.y + bt.y;
    o.z = (v[i].z - mean) * rstd * g.z + bt.z;
    o.w = (v[i].w - mean) * rstd * g.w + bt.w;
    *(float4*)(yr + (i * 64 + lane) * 4) = o;
  }
}

// ---------------------------------------------------------------------------
extern "C" void kernel_launch(void* const* d_in, const int* in_sizes, int n_in,
                              void* d_out, int out_size, void* d_ws,
                              size_t ws_size, hipStream_t stream) {
  const float* x = (const float*)d_in[0];
  const float* Wqkv = (const float*)d_in[1];
  const float* bqkv = (const float*)d_in[2];
  const float* Wproj = (const float*)d_in[3];
  const float* bproj = (const float*)d_in[4];
  const float* gamma = (const float*)d_in[5];
  const float* beta = (const float*)d_in[6];
  float* out = (float*)d_out;

  us* qkv = (us*)d_ws;                        // 16384*3072 (100.7 MB)
  us* attn = qkv + (size_t)16384 * 3072;      // 16384*1024 (33.6 MB)
  us* xb = attn + (size_t)16384 * 1024;       // 16384*1024 (33.6 MB)
  us* Wqkvb = xb + (size_t)16384 * 1024;      // 3072*1024  (6.3 MB)
  us* Wprojb = Wqkvb + (size_t)3072 * 1024;   // 1024*1024  (2.1 MB)
  const size_t need =
      ((size_t)16384 * 3072 + 3 * (size_t)16384 * 1024 + (size_t)3072 * 1024 +
       (size_t)1024 * 1024) * sizeof(us);

  if (ws_size >= need) {
    cast_bf16<<<(16384 * 1024 / 8 + 255) / 256, 256, 0, stream>>>(x, xb,
                                                                  16384 * 128);
    cast_bf16<<<(3072 * 1024 / 8 + 255) / 256, 256, 0, stream>>>(Wqkv, Wqkvb,
                                                                 3072 * 128);
    cast_bf16<<<(1024 * 1024 / 8 + 255) / 256, 256, 0, stream>>>(Wproj, Wprojb,
                                                                 1024 * 128);
    gemm256<3072, 1024, 0, 1, us><<<dim3(12, 64), 512, 0, stream>>>(
        xb, Wqkvb, bqkv, nullptr, qkv);
    attn_mfma<<<4096, 256, 0, stream>>>(qkv, attn);
    gemm256<1024, 1024, 1, 0, float><<<dim3(4, 64), 512, 0, stream>>>(
        attn, Wprojb, bproj, x, out);
  } else {
    gemm_bt<3072, 1024, 0, float, us><<<dim3(24, 128), 256, 0, stream>>>(
        x, Wqkv, bqkv, nullptr, qkv);
    attn_win<<<4096, 256, 0, stream>>>(qkv, attn);
    gemm_bt<1024, 1024, 1, us, float><<<dim3(8, 128), 256, 0, stream>>>(
        attn, Wproj, bproj, x, out);
  }
  ln_wave<<<4096, 256, 0, stream>>>(out, gamma, beta);
}